// Round 3
// baseline (1215.525 us; speedup 1.0000x reference)
//
#include <hip/hip_runtime.h>
#include <hip/hip_bf16.h>

typedef unsigned short u16;
typedef unsigned int   u32;
typedef __bf16 bf16x8 __attribute__((ext_vector_type(8)));
typedef float  f32x4  __attribute__((ext_vector_type(4)));

// Problem constants
#define M_TOK 100352      // B*N = 2*16*56*56 tokens
#define M_HALF 50176      // tokens per batch
#define DIMC  192
#define HIDC  768

__device__ __forceinline__ float b2f(u16 u) {
    u32 x = ((u32)u) << 16; float f; __builtin_memcpy(&f, &x, 4); return f;
}
__device__ __forceinline__ u16 f2b(float f) {
    u32 x; __builtin_memcpy(&x, &f, 4);
    x = x + 0x7FFFu + ((x >> 16) & 1u);   // round-to-nearest-even
    return (u16)(x >> 16);
}

// ---------------------------------------------------------------------------
// Weight prep: fp32 -> bf16, transpose to [N][K] for GEMM B-operand;
// depthwise weights [768][27] -> [27][768].
// ---------------------------------------------------------------------------
__global__ __launch_bounds__(256) void prep_weights(
    const float* __restrict__ qkv_w, const float* __restrict__ proj_w,
    const float* __restrict__ fc1_w, const float* __restrict__ fc2_w,
    const float* __restrict__ dw_w,
    u16* __restrict__ qkvt, u16* __restrict__ projt, u16* __restrict__ fc1t,
    u16* __restrict__ fc2t, u16* __restrict__ dwt)
{
    int id = blockIdx.x * 256 + threadIdx.x;
    if (id < 110592)      { int n = id / 192, k = id % 192;                 qkvt[id] = f2b(qkv_w[k * 576 + n]); }
    else if (id < 147456) { int e = id - 110592, n = e / 192, k = e % 192;  projt[e] = f2b(proj_w[k * 192 + n]); }
    else if (id < 294912) { int e = id - 147456, n = e / 192, k = e % 192;  fc1t[e]  = f2b(fc1_w[k * 768 + n]); }
    else if (id < 442368) { int e = id - 294912, n = e / 768, k = e % 768;  fc2t[e]  = f2b(fc2_w[k * 192 + n]); }
    else if (id < 463104) { int e = id - 442368, t = e / 768, c = e % 768;  dwt[e]   = f2b(dw_w[c * 27 + t]); }
}

// ---------------------------------------------------------------------------
// Relative-position bias matrix: bmat[head][i][j], i,j in [0,98)
// ---------------------------------------------------------------------------
__global__ __launch_bounds__(256) void biasmat_kernel(
    const float* __restrict__ btab, float* __restrict__ bmat)
{
    int id = blockIdx.x * 256 + threadIdx.x;
    if (id >= 98 * 98) return;
    int i = id / 98, j = id % 98;
    int di = i / 49, hi = (i / 7) % 7, wi = i % 7;
    int dj = j / 49, hj = (j / 7) % 7, wj = j % 7;
    int idx = (di - dj + 1) * 169 + (hi - hj + 6) * 13 + (wi - wj + 6);
    #pragma unroll
    for (int h = 0; h < 6; h++) bmat[h * 9604 + id] = btab[idx * 6 + h];
}

// ---------------------------------------------------------------------------
// LayerNorm over 192; one wave per row. PERM=true writes window-major order.
// BF_IN selects bf16 vs f32 input.
// ---------------------------------------------------------------------------
template<bool PERM, bool BF_IN>
__global__ __launch_bounds__(256) void ln_kernel(
    const void* __restrict__ xin, const float* __restrict__ g,
    const float* __restrict__ bb, u16* __restrict__ out)
{
    int row  = blockIdx.x * 4 + (threadIdx.x >> 6);
    int lane = threadIdx.x & 63;
    float v0, v1, v2;
    if (BF_IN) {
        const u16* xr = (const u16*)xin + (size_t)row * DIMC;
        v0 = b2f(xr[lane]); v1 = b2f(xr[lane + 64]); v2 = b2f(xr[lane + 128]);
    } else {
        const float* xr = (const float*)xin + (size_t)row * DIMC;
        v0 = xr[lane]; v1 = xr[lane + 64]; v2 = xr[lane + 128];
    }
    float s  = v0 + v1 + v2;
    float s2 = v0 * v0 + v1 * v1 + v2 * v2;
    #pragma unroll
    for (int m = 1; m < 64; m <<= 1) { s += __shfl_xor(s, m); s2 += __shfl_xor(s2, m); }
    float mu = s * (1.0f / 192.0f);
    float rs = rsqrtf(s2 * (1.0f / 192.0f) - mu * mu + 1e-5f);
    size_t ob;
    if (PERM) {
        int b = row / 50176, r = row % 50176;
        int d = r / 3136, r2 = r % 3136, h = r2 / 56, w = r2 % 56;
        int widx = ((b * 8 + (d >> 1)) * 8 + h / 7) * 8 + w / 7;
        int tok  = (d & 1) * 49 + (h % 7) * 7 + (w % 7);
        ob = ((size_t)widx * 98 + tok) * DIMC;
    } else {
        ob = (size_t)row * DIMC;
    }
    out[ob + lane]       = f2b((v0 - mu) * rs * g[lane]       + bb[lane]);
    out[ob + lane + 64]  = f2b((v1 - mu) * rs * g[lane + 64]  + bb[lane + 64]);
    out[ob + lane + 128] = f2b((v2 - mu) * rs * g[lane + 128] + bb[lane + 128]);
}

// ---------------------------------------------------------------------------
// bf16 MFMA GEMM: C[M,N] = A[M,K] * Bt[N,K]^T + bias
// BM=128, BN=64, BK=32, 256 threads (4 waves, 2x2), per-wave 64x32 (acc 4x2).
// EPI 0: write bf16 outb[row*N+col]
// EPI 1: proj — window-reverse row -> gg; x2b[gg] = bf16(xres[gg] + 0.5*v)  (N==192)
// EPI 2: fc2  — outf[(row+mofs)*N+col] = b2f(x2b[...]) + 0.5*v              (N==192)
// ---------------------------------------------------------------------------
template<int EPI>
__global__ __launch_bounds__(256) void gemm_bt(
    const u16* __restrict__ A, const u16* __restrict__ Bt,
    const float* __restrict__ bias, int K, int N,
    u16* __restrict__ outb, const float* __restrict__ xres,
    u16* __restrict__ x2b, float* __restrict__ outf, int mofs)
{
    __shared__ __align__(16) u16 Alds[128 * 32];
    __shared__ __align__(16) u16 Blds[64 * 32];
    int m0 = blockIdx.x * 128;
    int n0 = blockIdx.y * 64;
    int t  = threadIdx.x;
    int ar = t >> 2, ac = (t & 3) * 8;
    int lane = t & 63, wid = t >> 6;
    int wm = wid >> 1, wn = wid & 1;
    int lrow = lane & 15, lko = (lane >> 4) * 8;
    const u16* Ab  = A  + (size_t)(m0 + ar) * K + ac;
    const u16* Ab2 = Ab + (size_t)64 * K;
    const u16* Bb  = Bt + (size_t)(n0 + ar) * K + ac;
    f32x4 acc[4][2] = {};
    for (int kt = 0; kt < K; kt += 32) {
        uint4 a0 = *(const uint4*)(Ab  + kt);
        uint4 a1 = *(const uint4*)(Ab2 + kt);
        uint4 b0 = *(const uint4*)(Bb  + kt);
        __syncthreads();
        ((uint4*)Alds)[t]       = a0;
        ((uint4*)Alds)[256 + t] = a1;
        ((uint4*)Blds)[t]       = b0;
        __syncthreads();
        bf16x8 af[4], bfr[2];
        #pragma unroll
        for (int mi = 0; mi < 4; mi++)
            af[mi] = *(const bf16x8*)&Alds[(wm * 64 + mi * 16 + lrow) * 32 + lko];
        #pragma unroll
        for (int ni = 0; ni < 2; ni++)
            bfr[ni] = *(const bf16x8*)&Blds[(wn * 32 + ni * 16 + lrow) * 32 + lko];
        #pragma unroll
        for (int mi = 0; mi < 4; mi++)
            #pragma unroll
            for (int ni = 0; ni < 2; ni++)
                acc[mi][ni] = __builtin_amdgcn_mfma_f32_16x16x32_bf16(af[mi], bfr[ni], acc[mi][ni], 0, 0, 0);
    }
    int r0 = (lane >> 4) * 4, cl = lane & 15;
    #pragma unroll
    for (int ni = 0; ni < 2; ni++) {
        int col = n0 + wn * 32 + ni * 16 + cl;
        float bv = bias[col];
        #pragma unroll
        for (int mi = 0; mi < 4; mi++) {
            #pragma unroll
            for (int r = 0; r < 4; r++) {
                int row = m0 + wm * 64 + mi * 16 + r0 + r;
                float v = acc[mi][ni][r] + bv;
                if (EPI == 0) {
                    outb[(size_t)row * N + col] = f2b(v);
                } else if (EPI == 1) {
                    int widx = row / 98, tok = row % 98;
                    int b = widx >> 9, rem = widx & 511;
                    int bd = rem >> 6, bh = (rem >> 3) & 7, bw = rem & 7;
                    int td = tok / 49, rr = tok % 49, th = rr / 7, tw = rr % 7;
                    int d = bd * 2 + td, h = bh * 7 + th, w = bw * 7 + tw;
                    size_t gg = ((size_t)b * 50176 + (d * 56 + h) * 56 + w) * (size_t)N + col;
                    x2b[gg] = f2b(xres[gg] + 0.5f * v);
                } else {
                    size_t gg = (size_t)(row + mofs) * N + col;
                    outf[gg] = b2f(x2b[gg]) + 0.5f * v;
                }
            }
        }
    }
}

// ---------------------------------------------------------------------------
// Window attention: block = (window, head), 128 threads, thread-per-row.
// Two-pass softmax (recompute scores), K/V staged fp32 in LDS.
// ---------------------------------------------------------------------------
__global__ __launch_bounds__(128) void attn_kernel(
    const u16* __restrict__ qkv, const float* __restrict__ bmat, u16* __restrict__ outb)
{
    __shared__ __align__(16) float Ksm[98][36];
    __shared__ __align__(16) float Vsm[98][36];
    int widx = blockIdx.x, head = blockIdx.y;
    int tid  = threadIdx.x;
    size_t base = (size_t)widx * 98 * 576 + head * 32;
    for (int e = tid; e < 98 * 4; e += 128) {
        int rr = e >> 2, seg = (e & 3) * 8;
        uint4 kr = *(const uint4*)(qkv + base + (size_t)rr * 576 + 192 + seg);
        uint4 vr = *(const uint4*)(qkv + base + (size_t)rr * 576 + 384 + seg);
        const u16* kp = (const u16*)&kr;
        const u16* vp = (const u16*)&vr;
        #pragma unroll
        for (int u = 0; u < 8; u++) { Ksm[rr][seg + u] = b2f(kp[u]); Vsm[rr][seg + u] = b2f(vp[u]); }
    }
    __syncthreads();
    int i = tid;
    if (i >= 98) return;
    float q[32];
    {
        const u16* qp = qkv + base + (size_t)i * 576;
        #pragma unroll
        for (int sg = 0; sg < 4; sg++) {
            uint4 raw = *(const uint4*)(qp + sg * 8);
            const u16* pp = (const u16*)&raw;
            #pragma unroll
            for (int u = 0; u < 8; u++) q[sg * 8 + u] = b2f(pp[u]) * 0.17677669529663688f; // 32^-0.5
        }
    }
    const float* brow = bmat + ((size_t)head * 98 + i) * 98;
    float mx = -1e30f;
    for (int j = 0; j < 98; j++) {
        float s0 = 0.f, s1 = 0.f, s2 = 0.f, s3 = 0.f;
        #pragma unroll
        for (int dd = 0; dd < 32; dd += 4) {
            float4 kk = *(const float4*)&Ksm[j][dd];
            s0 += q[dd] * kk.x; s1 += q[dd + 1] * kk.y; s2 += q[dd + 2] * kk.z; s3 += q[dd + 3] * kk.w;
        }
        mx = fmaxf(mx, (s0 + s1) + (s2 + s3) + brow[j]);
    }
    float acc[32];
    #pragma unroll
    for (int u = 0; u < 32; u++) acc[u] = 0.f;
    float sum = 0.f;
    for (int j = 0; j < 98; j++) {
        float s0 = 0.f, s1 = 0.f, s2 = 0.f, s3 = 0.f;
        #pragma unroll
        for (int dd = 0; dd < 32; dd += 4) {
            float4 kk = *(const float4*)&Ksm[j][dd];
            s0 += q[dd] * kk.x; s1 += q[dd + 1] * kk.y; s2 += q[dd + 2] * kk.z; s3 += q[dd + 3] * kk.w;
        }
        float p = __expf((s0 + s1) + (s2 + s3) + brow[j] - mx);
        sum += p;
        #pragma unroll
        for (int dd = 0; dd < 32; dd += 4) {
            float4 vv = *(const float4*)&Vsm[j][dd];
            acc[dd] += p * vv.x; acc[dd + 1] += p * vv.y; acc[dd + 2] += p * vv.z; acc[dd + 3] += p * vv.w;
        }
    }
    float rinv = 1.0f / sum;
    u16* op = outb + ((size_t)widx * 98 + i) * DIMC + head * 32;
    #pragma unroll
    for (int dd = 0; dd < 32; dd += 2) {
        u32 pk = (u32)f2b(acc[dd] * rinv) | ((u32)f2b(acc[dd + 1] * rinv) << 16);
        *(u32*)(op + dd) = pk;
    }
}

// ---------------------------------------------------------------------------
// Depthwise 3x3x3 conv (channel-last) + exact GELU, one batch chunk.
// hid/gelu are [50176][768] (batch-local). 8 channels/thread.
// ---------------------------------------------------------------------------
__global__ __launch_bounds__(256) void dwconv_gelu_kernel(
    const u16* __restrict__ hid, const u16* __restrict__ dwt,
    const float* __restrict__ dwb, u16* __restrict__ outb)
{
    int gid = blockIdx.x * 256 + threadIdx.x;
    int token = gid / 96;              // [0, 50176)
    int cg = gid - token * 96;
    int c0 = cg * 8;
    int d = token / 3136;
    int r2 = token - d * 3136;
    int h = r2 / 56;
    int w = r2 - h * 56;
    float acc[8];
    float4 bv0 = *(const float4*)(dwb + c0);
    float4 bv1 = *(const float4*)(dwb + c0 + 4);
    acc[0] = bv0.x; acc[1] = bv0.y; acc[2] = bv0.z; acc[3] = bv0.w;
    acc[4] = bv1.x; acc[5] = bv1.y; acc[6] = bv1.z; acc[7] = bv1.w;
    #pragma unroll
    for (int dz = 0; dz < 3; dz++) {
        int zz = d + dz - 1;
        if ((unsigned)zz >= 16u) continue;
        #pragma unroll
        for (int dy = 0; dy < 3; dy++) {
            int yy = h + dy - 1;
            if ((unsigned)yy >= 56u) continue;
            #pragma unroll
            for (int dx = 0; dx < 3; dx++) {
                int xx = w + dx - 1;
                if ((unsigned)xx >= 56u) continue;
                size_t nb = ((size_t)zz * 56 + yy) * 56 + xx;
                uint4 iv = *(const uint4*)(hid + nb * HIDC + c0);
                uint4 wv = *(const uint4*)(dwt + (size_t)(dz * 9 + dy * 3 + dx) * HIDC + c0);
                const u16* ip = (const u16*)&iv;
                const u16* wq = (const u16*)&wv;
                #pragma unroll
                for (int u = 0; u < 8; u++) acc[u] += b2f(ip[u]) * b2f(wq[u]);
            }
        }
    }
    u16 res[8];
    #pragma unroll
    for (int u = 0; u < 8; u++) {
        float a = acc[u];
        res[u] = f2b(0.5f * a * (1.0f + erff(a * 0.70710678118654752f)));
    }
    uint4 ov;
    u32* op = (u32*)&ov;
    op[0] = (u32)res[0] | ((u32)res[1] << 16);
    op[1] = (u32)res[2] | ((u32)res[3] << 16);
    op[2] = (u32)res[4] | ((u32)res[5] << 16);
    op[3] = (u32)res[6] | ((u32)res[7] << 16);
    *(uint4*)(outb + (size_t)token * HIDC + c0) = ov;
}

// ---------------------------------------------------------------------------
// Orchestration. Workspace layout (bytes) — lifetime-aliased, 232.4 MB total:
//   [0,        1,156,704)   weights (bf16) + bias matrix (f32)
//   [1,160,192, 39,695,360) R1: xw (LN1 out) -> attnb (attn out) -> h2 (LN2 out)
//   [39,695,360,155,300,864) R2: qkvb; after attn dies:
//        x2 bf16 at 39,695,360 (+38,535,168)
//        hid_c   at 78,230,528 (+77,070,336)  per-batch FC1 out
//   [155,300,864,232,371,200) gelu_c per-batch dwconv+gelu out
// FFN is chunked over the 2 batches (dw conv never crosses batch).
// ---------------------------------------------------------------------------
extern "C" void kernel_launch(void* const* d_in, const int* in_sizes, int n_in,
                              void* d_out, int out_size, void* d_ws, size_t ws_size,
                              hipStream_t stream)
{
    const float* x      = (const float*)d_in[0];
    const float* n1g    = (const float*)d_in[1];
    const float* n1b    = (const float*)d_in[2];
    const float* qkv_w  = (const float*)d_in[3];
    const float* qkv_b  = (const float*)d_in[4];
    const float* btab   = (const float*)d_in[5];
    const float* proj_w = (const float*)d_in[6];
    const float* proj_b = (const float*)d_in[7];
    const float* n2g    = (const float*)d_in[8];
    const float* n2b    = (const float*)d_in[9];
    const float* fc1_w  = (const float*)d_in[10];
    const float* fc1_b  = (const float*)d_in[11];
    const float* dw_w   = (const float*)d_in[12];
    const float* dw_b   = (const float*)d_in[13];
    const float* fc2_w  = (const float*)d_in[14];
    const float* fc2_b  = (const float*)d_in[15];

    char* ws = (char*)d_ws;
    u16*   qkvt  = (u16*)(ws);
    u16*   projt = (u16*)(ws + 221184);
    u16*   fc1t  = (u16*)(ws + 294912);
    u16*   fc2t  = (u16*)(ws + 589824);
    u16*   dwt   = (u16*)(ws + 884736);
    float* bmat  = (float*)(ws + 926208);
    u16*   r1    = (u16*)(ws + 1160192);      // xw / attnb / h2 (38,535,168 B)
    u16*   qkvb  = (u16*)(ws + 39695360LL);   // 115,605,504 B
    u16*   x2b   = (u16*)(ws + 39695360LL);   // bf16 residual (aliases dead qkvb)
    u16*   hid_c = (u16*)(ws + 78230528LL);   // per-batch [50176][768] bf16
    u16*   gelu_c= (u16*)(ws + 155300864LL);  // per-batch [50176][768] bf16

    prep_weights<<<dim3(1809), dim3(256), 0, stream>>>(qkv_w, proj_w, fc1_w, fc2_w, dw_w,
                                                       qkvt, projt, fc1t, fc2t, dwt);
    biasmat_kernel<<<dim3(38), dim3(256), 0, stream>>>(btab, bmat);
    // LN1 (window-permuted) -> r1
    ln_kernel<true, false><<<dim3(25088), dim3(256), 0, stream>>>(x, n1g, n1b, r1);
    // QKV GEMM: r1 -> qkvb
    gemm_bt<0><<<dim3(784, 9), dim3(256), 0, stream>>>(r1, qkvt, qkv_b, 192, 576,
                                                       qkvb, nullptr, nullptr, nullptr, 0);
    // Attention: qkvb -> r1 (attnb)
    attn_kernel<<<dim3(1024, 6), dim3(128), 0, stream>>>(qkvb, bmat, r1);
    // Proj GEMM + window-reverse + residual: r1, x -> x2b (bf16)
    gemm_bt<1><<<dim3(784, 3), dim3(256), 0, stream>>>(r1, projt, proj_b, 192, 192,
                                                       nullptr, x, x2b, nullptr, 0);
    // LN2: x2b -> r1 (h2)
    ln_kernel<false, true><<<dim3(25088), dim3(256), 0, stream>>>(x2b, n2g, n2b, r1);
    // FFN chunked over batch
    for (int b = 0; b < 2; b++) {
        const u16* h2c = r1 + (size_t)b * M_HALF * DIMC;
        gemm_bt<0><<<dim3(392, 12), dim3(256), 0, stream>>>(h2c, fc1t, fc1_b, 192, 768,
                                                            hid_c, nullptr, nullptr, nullptr, 0);
        dwconv_gelu_kernel<<<dim3(18816), dim3(256), 0, stream>>>(hid_c, dwt, dw_b, gelu_c);
        gemm_bt<2><<<dim3(392, 3), dim3(256), 0, stream>>>(gelu_c, fc2t, fc2_b, 768, 192,
                                                           nullptr, nullptr, x2b, (float*)d_out,
                                                           b * M_HALF);
    }
}

// Round 4
// 900.174 us; speedup vs baseline: 1.3503x; 1.3503x over previous
//
#include <hip/hip_runtime.h>
#include <hip/hip_bf16.h>

typedef unsigned short u16;
typedef unsigned int   u32;
typedef __bf16 bf16x8 __attribute__((ext_vector_type(8)));
typedef float  f32x4  __attribute__((ext_vector_type(4)));

// Problem constants
#define M_TOK 100352      // B*N = 2*16*56*56 tokens
#define M_HALF 50176      // tokens per batch
#define DIMC  192
#define HIDC  768
#define SCALE_F 0.17677669529663688f

__device__ __forceinline__ float b2f(u16 u) {
    u32 x = ((u32)u) << 16; float f; __builtin_memcpy(&f, &x, 4); return f;
}
__device__ __forceinline__ u16 f2b(float f) {
    u32 x; __builtin_memcpy(&x, &f, 4);
    x = x + 0x7FFFu + ((x >> 16) & 1u);   // round-to-nearest-even
    return (u16)(x >> 16);
}

// ---------------------------------------------------------------------------
// Weight prep: fp32 -> bf16, transpose to [N][K] for GEMM B-operand;
// depthwise weights [768][27] -> [27][768].
// ---------------------------------------------------------------------------
__global__ __launch_bounds__(256) void prep_weights(
    const float* __restrict__ qkv_w, const float* __restrict__ proj_w,
    const float* __restrict__ fc1_w, const float* __restrict__ fc2_w,
    const float* __restrict__ dw_w,
    u16* __restrict__ qkvt, u16* __restrict__ projt, u16* __restrict__ fc1t,
    u16* __restrict__ fc2t, u16* __restrict__ dwt)
{
    int id = blockIdx.x * 256 + threadIdx.x;
    if (id < 110592)      { int n = id / 192, k = id % 192;                 qkvt[id] = f2b(qkv_w[k * 576 + n]); }
    else if (id < 147456) { int e = id - 110592, n = e / 192, k = e % 192;  projt[e] = f2b(proj_w[k * 192 + n]); }
    else if (id < 294912) { int e = id - 147456, n = e / 192, k = e % 192;  fc1t[e]  = f2b(fc1_w[k * 768 + n]); }
    else if (id < 442368) { int e = id - 294912, n = e / 768, k = e % 768;  fc2t[e]  = f2b(fc2_w[k * 192 + n]); }
    else if (id < 463104) { int e = id - 442368, t = e / 768, c = e % 768;  dwt[e]   = f2b(dw_w[c * 27 + t]); }
}

// ---------------------------------------------------------------------------
// Relative-position bias matrix, PADDED: bmat[head][112][112] f32.
//   j >= 98           -> -1e30 (pad cols: p = exp(-inf) = 0)
//   i >= 98 (j < 98)  -> 0     (pad rows: sane values, rows discarded)
// ---------------------------------------------------------------------------
__global__ __launch_bounds__(256) void biasmat_kernel(
    const float* __restrict__ btab, float* __restrict__ bmat)
{
    int id = blockIdx.x * 256 + threadIdx.x;
    if (id >= 6 * 112 * 112) return;
    int h = id / 12544, rem = id % 12544, i = rem / 112, j = rem % 112;
    float v;
    if (j >= 98)      v = -1e30f;
    else if (i >= 98) v = 0.0f;
    else {
        int di = i / 49, hi = (i / 7) % 7, wi = i % 7;
        int dj = j / 49, hj = (j / 7) % 7, wj = j % 7;
        int idx = (di - dj + 1) * 169 + (hi - hj + 6) * 13 + (wi - wj + 6);
        v = btab[idx * 6 + h];
    }
    bmat[id] = v;
}

// ---------------------------------------------------------------------------
// LayerNorm over 192; one wave per row. PERM=true writes window-major order.
// BF_IN selects bf16 vs f32 input.
// ---------------------------------------------------------------------------
template<bool PERM, bool BF_IN>
__global__ __launch_bounds__(256) void ln_kernel(
    const void* __restrict__ xin, const float* __restrict__ g,
    const float* __restrict__ bb, u16* __restrict__ out)
{
    int row  = blockIdx.x * 4 + (threadIdx.x >> 6);
    int lane = threadIdx.x & 63;
    float v0, v1, v2;
    if (BF_IN) {
        const u16* xr = (const u16*)xin + (size_t)row * DIMC;
        v0 = b2f(xr[lane]); v1 = b2f(xr[lane + 64]); v2 = b2f(xr[lane + 128]);
    } else {
        const float* xr = (const float*)xin + (size_t)row * DIMC;
        v0 = xr[lane]; v1 = xr[lane + 64]; v2 = xr[lane + 128];
    }
    float s  = v0 + v1 + v2;
    float s2 = v0 * v0 + v1 * v1 + v2 * v2;
    #pragma unroll
    for (int m = 1; m < 64; m <<= 1) { s += __shfl_xor(s, m); s2 += __shfl_xor(s2, m); }
    float mu = s * (1.0f / 192.0f);
    float rs = rsqrtf(s2 * (1.0f / 192.0f) - mu * mu + 1e-5f);
    size_t ob;
    if (PERM) {
        int b = row / 50176, r = row % 50176;
        int d = r / 3136, r2 = r % 3136, h = r2 / 56, w = r2 % 56;
        int widx = ((b * 8 + (d >> 1)) * 8 + h / 7) * 8 + w / 7;
        int tok  = (d & 1) * 49 + (h % 7) * 7 + (w % 7);
        ob = ((size_t)widx * 98 + tok) * DIMC;
    } else {
        ob = (size_t)row * DIMC;
    }
    out[ob + lane]       = f2b((v0 - mu) * rs * g[lane]       + bb[lane]);
    out[ob + lane + 64]  = f2b((v1 - mu) * rs * g[lane + 64]  + bb[lane + 64]);
    out[ob + lane + 128] = f2b((v2 - mu) * rs * g[lane + 128] + bb[lane + 128]);
}

// ---------------------------------------------------------------------------
// bf16 MFMA GEMM: C[M,N] = A[M,K] * Bt[N,K]^T + bias  (unchanged, verified)
// ---------------------------------------------------------------------------
template<int EPI>
__global__ __launch_bounds__(256) void gemm_bt(
    const u16* __restrict__ A, const u16* __restrict__ Bt,
    const float* __restrict__ bias, int K, int N,
    u16* __restrict__ outb, const float* __restrict__ xres,
    u16* __restrict__ x2b, float* __restrict__ outf, int mofs)
{
    __shared__ __align__(16) u16 Alds[128 * 32];
    __shared__ __align__(16) u16 Blds[64 * 32];
    int m0 = blockIdx.x * 128;
    int n0 = blockIdx.y * 64;
    int t  = threadIdx.x;
    int ar = t >> 2, ac = (t & 3) * 8;
    int lane = t & 63, wid = t >> 6;
    int wm = wid >> 1, wn = wid & 1;
    int lrow = lane & 15, lko = (lane >> 4) * 8;
    const u16* Ab  = A  + (size_t)(m0 + ar) * K + ac;
    const u16* Ab2 = Ab + (size_t)64 * K;
    const u16* Bb  = Bt + (size_t)(n0 + ar) * K + ac;
    f32x4 acc[4][2] = {};
    for (int kt = 0; kt < K; kt += 32) {
        uint4 a0 = *(const uint4*)(Ab  + kt);
        uint4 a1 = *(const uint4*)(Ab2 + kt);
        uint4 b0 = *(const uint4*)(Bb  + kt);
        __syncthreads();
        ((uint4*)Alds)[t]       = a0;
        ((uint4*)Alds)[256 + t] = a1;
        ((uint4*)Blds)[t]       = b0;
        __syncthreads();
        bf16x8 af[4], bfr[2];
        #pragma unroll
        for (int mi = 0; mi < 4; mi++)
            af[mi] = *(const bf16x8*)&Alds[(wm * 64 + mi * 16 + lrow) * 32 + lko];
        #pragma unroll
        for (int ni = 0; ni < 2; ni++)
            bfr[ni] = *(const bf16x8*)&Blds[(wn * 32 + ni * 16 + lrow) * 32 + lko];
        #pragma unroll
        for (int mi = 0; mi < 4; mi++)
            #pragma unroll
            for (int ni = 0; ni < 2; ni++)
                acc[mi][ni] = __builtin_amdgcn_mfma_f32_16x16x32_bf16(af[mi], bfr[ni], acc[mi][ni], 0, 0, 0);
    }
    int r0 = (lane >> 4) * 4, cl = lane & 15;
    #pragma unroll
    for (int ni = 0; ni < 2; ni++) {
        int col = n0 + wn * 32 + ni * 16 + cl;
        float bv = bias[col];
        #pragma unroll
        for (int mi = 0; mi < 4; mi++) {
            #pragma unroll
            for (int r = 0; r < 4; r++) {
                int row = m0 + wm * 64 + mi * 16 + r0 + r;
                float v = acc[mi][ni][r] + bv;
                if (EPI == 0) {
                    outb[(size_t)row * N + col] = f2b(v);
                } else if (EPI == 1) {
                    int widx = row / 98, tok = row % 98;
                    int b = widx >> 9, rem = widx & 511;
                    int bd = rem >> 6, bh = (rem >> 3) & 7, bw = rem & 7;
                    int td = tok / 49, rr = tok % 49, th = rr / 7, tw = rr % 7;
                    int d = bd * 2 + td, h = bh * 7 + th, w = bw * 7 + tw;
                    size_t gg = ((size_t)b * 50176 + (d * 56 + h) * 56 + w) * (size_t)N + col;
                    x2b[gg] = f2b(xres[gg] + 0.5f * v);
                } else {
                    size_t gg = (size_t)(row + mofs) * N + col;
                    outf[gg] = b2f(x2b[gg]) + 0.5f * v;
                }
            }
        }
    }
}

// ---------------------------------------------------------------------------
// MFMA window attention: 1 wave per (window, head). 98 tokens padded to 112.
// QK^T: S[112][112] via 7x7 grid of 16x16x32 MFMA (d=32 = one K-step).
// Softmax in C-layout regs (shfl_xor over 16-lane col groups).
// PV: P staged bf16 in LDS (C->A transpose), V staged TRANSPOSED (Vt[d][j]),
//     O[112][32] via 2x4 k-step MFMAs per row-tile.
// LDS: Klds 112x40 (pad->2-way banks), Vt 32x136 + XOR swz, Plds 16x136 + swz.
// ---------------------------------------------------------------------------
__global__ __launch_bounds__(64) void attn_mfma_kernel(
    const u16* __restrict__ qkv, const float* __restrict__ bmat,
    u16* __restrict__ outb)
{
    __shared__ __align__(16) u16 Klds[112 * 40];
    __shared__ __align__(16) u16 Vt[32 * 136];
    __shared__ __align__(16) u16 Plds[16 * 136];
    int widx = blockIdx.x, head = blockIdx.y;
    int l = threadIdx.x;
    int c = l & 15, g = l >> 4;
    size_t wbase = (size_t)widx * (98 * 576) + head * 32;

    // --- stage K rows (zero-padded) + V transposed (swizzled) ---
    for (int e = l; e < 448; e += 64) {
        int rr = e >> 2, seg = (e & 3) * 8;
        uint4 kr = {0, 0, 0, 0}, vr = {0, 0, 0, 0};
        if (rr < 98) {
            kr = *(const uint4*)(qkv + wbase + (size_t)rr * 576 + 192 + seg);
            vr = *(const uint4*)(qkv + wbase + (size_t)rr * 576 + 384 + seg);
        }
        *(uint4*)&Klds[rr * 40 + seg] = kr;
        int sw = ((seg >> 3) & 3) << 4;          // = ((d>>3)&3)<<4, d=seg+u
        int pc = rr ^ sw;                         // swizzled column (j)
        const u16* vp = (const u16*)&vr;
        #pragma unroll
        for (int u = 0; u < 8; u++)
            Vt[(seg + u) * 136 + pc] = vp[u];
    }
    // zero logical j in [112,128) of Vt (so PV k-pad contributes exact 0)
    {
        int d = l >> 1, half = l & 1;            // 64 tasks: 32 rows x 2
        int sw = ((d >> 3) & 3) << 4;
        uint4 z = {0, 0, 0, 0};
        *(uint4*)&Vt[d * 136 + ((112 + 8 * half) ^ sw)] = z;
        if (l < 32) {
            int i = l >> 1; half = l & 1;        // 32 tasks: 16 rows x 2
            int swp = ((i >> 2) & 3) << 4;
            *(uint4*)&Plds[i * 136 + ((112 + 8 * half) ^ swp)] = z;
        }
    }

    // --- per row-tile: QK^T -> softmax -> PV ---
    for (int it = 0; it < 7; ++it) {
        int qtok = 16 * it + c; if (qtok > 97) qtok = 97;   // clamp pad rows
        bf16x8 qf = *(const bf16x8*)(qkv + wbase + (size_t)qtok * 576 + g * 8);
        f32x4 s[7];
        f32x4 z = {};
        #pragma unroll
        for (int jt = 0; jt < 7; ++jt) {
            bf16x8 kf = *(const bf16x8*)&Klds[(16 * jt + c) * 40 + g * 8];
            s[jt] = __builtin_amdgcn_mfma_f32_16x16x32_bf16(qf, kf, z, 0, 0, 0);
        }
        // bias + scale, row-max, exp, row-sum (rows = 16it+4g+r, cols = 16jt+c)
        const float* bb = bmat + ((size_t)head * 112 + 16 * it + 4 * g) * 112 + c;
        float sm[4];
        #pragma unroll
        for (int r = 0; r < 4; ++r) {
            float m = -1e30f;
            #pragma unroll
            for (int jt = 0; jt < 7; ++jt) {
                float v = s[jt][r] * SCALE_F + bb[r * 112 + 16 * jt];
                s[jt][r] = v;
                m = fmaxf(m, v);
            }
            m = fmaxf(m, __shfl_xor(m, 1)); m = fmaxf(m, __shfl_xor(m, 2));
            m = fmaxf(m, __shfl_xor(m, 4)); m = fmaxf(m, __shfl_xor(m, 8));
            float su = 0.f;
            #pragma unroll
            for (int jt = 0; jt < 7; ++jt) {
                float p = __expf(s[jt][r] - m);
                s[jt][r] = p;
                su += p;
            }
            su += __shfl_xor(su, 1); su += __shfl_xor(su, 2);
            su += __shfl_xor(su, 4); su += __shfl_xor(su, 8);
            sm[r] = su;
        }
        // write P (bf16) to LDS: C-layout -> A-layout transpose
        #pragma unroll
        for (int r = 0; r < 4; ++r) {
            int prow = 4 * g + r;
            int swp = ((prow >> 2) & 3) << 4;
            #pragma unroll
            for (int jt = 0; jt < 7; ++jt)
                Plds[prow * 136 + ((16 * jt + c) ^ swp)] = f2b(s[jt][r]);
        }
        // PV: O[16 x 32] = P[16 x 128] * Vt^T
        bf16x8 pa[4];
        int swr = ((c >> 2) & 3) << 4;
        #pragma unroll
        for (int ks = 0; ks < 4; ++ks)
            pa[ks] = *(const bf16x8*)&Plds[c * 136 + ((32 * ks + 8 * g) ^ swr)];
        #pragma unroll
        for (int dt = 0; dt < 2; ++dt) {
            f32x4 o = {};
            int vrow = 16 * dt + c;
            int swv = ((vrow >> 3) & 3) << 4;
            #pragma unroll
            for (int ks = 0; ks < 4; ++ks) {
                bf16x8 vb = *(const bf16x8*)&Vt[vrow * 136 + ((32 * ks + 8 * g) ^ swv)];
                o = __builtin_amdgcn_mfma_f32_16x16x32_bf16(pa[ks], vb, o, 0, 0, 0);
            }
            #pragma unroll
            for (int r = 0; r < 4; ++r) {
                int row = 16 * it + 4 * g + r;
                if (row < 98)
                    outb[((size_t)widx * 98 + row) * DIMC + head * 32 + 16 * dt + c]
                        = f2b(o[r] / sm[r]);
            }
        }
    }
}

// ---------------------------------------------------------------------------
// Depthwise 3x3x3 conv (channel-last) + exact GELU, one batch chunk.
// ---------------------------------------------------------------------------
__global__ __launch_bounds__(256) void dwconv_gelu_kernel(
    const u16* __restrict__ hid, const u16* __restrict__ dwt,
    const float* __restrict__ dwb, u16* __restrict__ outb)
{
    int gid = blockIdx.x * 256 + threadIdx.x;
    int token = gid / 96;              // [0, 50176)
    int cg = gid - token * 96;
    int c0 = cg * 8;
    int d = token / 3136;
    int r2 = token - d * 3136;
    int h = r2 / 56;
    int w = r2 - h * 56;
    float acc[8];
    float4 bv0 = *(const float4*)(dwb + c0);
    float4 bv1 = *(const float4*)(dwb + c0 + 4);
    acc[0] = bv0.x; acc[1] = bv0.y; acc[2] = bv0.z; acc[3] = bv0.w;
    acc[4] = bv1.x; acc[5] = bv1.y; acc[6] = bv1.z; acc[7] = bv1.w;
    #pragma unroll
    for (int dz = 0; dz < 3; dz++) {
        int zz = d + dz - 1;
        if ((unsigned)zz >= 16u) continue;
        #pragma unroll
        for (int dy = 0; dy < 3; dy++) {
            int yy = h + dy - 1;
            if ((unsigned)yy >= 56u) continue;
            #pragma unroll
            for (int dx = 0; dx < 3; dx++) {
                int xx = w + dx - 1;
                if ((unsigned)xx >= 56u) continue;
                size_t nb = ((size_t)zz * 56 + yy) * 56 + xx;
                uint4 iv = *(const uint4*)(hid + nb * HIDC + c0);
                uint4 wv = *(const uint4*)(dwt + (size_t)(dz * 9 + dy * 3 + dx) * HIDC + c0);
                const u16* ip = (const u16*)&iv;
                const u16* wq = (const u16*)&wv;
                #pragma unroll
                for (int u = 0; u < 8; u++) acc[u] += b2f(ip[u]) * b2f(wq[u]);
            }
        }
    }
    u16 res[8];
    #pragma unroll
    for (int u = 0; u < 8; u++) {
        float a = acc[u];
        res[u] = f2b(0.5f * a * (1.0f + erff(a * 0.70710678118654752f)));
    }
    uint4 ov;
    u32* op = (u32*)&ov;
    op[0] = (u32)res[0] | ((u32)res[1] << 16);
    op[1] = (u32)res[2] | ((u32)res[3] << 16);
    op[2] = (u32)res[4] | ((u32)res[5] << 16);
    op[3] = (u32)res[6] | ((u32)res[7] << 16);
    *(uint4*)(outb + (size_t)token * HIDC + c0) = ov;
}

// ---------------------------------------------------------------------------
// Orchestration. Workspace layout (bytes) — lifetime-aliased, 232.4 MB total:
//   [0,        926,208)     weights (bf16)
//   [1,160,192, 39,695,360) R1: xw (LN1 out) -> attnb (attn out) -> h2 (LN2 out)
//   [39,695,360,155,300,864) R2: qkvb; after attn dies:
//        x2b bf16 at 39,695,360 (+38,535,168)
//        hid_c    at 78,230,528 (+77,070,336)  per-batch FC1 out
//   [155,300,864,232,371,200) bmat (301,056 B, dead after attn) then gelu_c
// FFN is chunked over the 2 batches (dw conv never crosses batch).
// ---------------------------------------------------------------------------
extern "C" void kernel_launch(void* const* d_in, const int* in_sizes, int n_in,
                              void* d_out, int out_size, void* d_ws, size_t ws_size,
                              hipStream_t stream)
{
    const float* x      = (const float*)d_in[0];
    const float* n1g    = (const float*)d_in[1];
    const float* n1b    = (const float*)d_in[2];
    const float* qkv_w  = (const float*)d_in[3];
    const float* qkv_b  = (const float*)d_in[4];
    const float* btab   = (const float*)d_in[5];
    const float* proj_w = (const float*)d_in[6];
    const float* proj_b = (const float*)d_in[7];
    const float* n2g    = (const float*)d_in[8];
    const float* n2b    = (const float*)d_in[9];
    const float* fc1_w  = (const float*)d_in[10];
    const float* fc1_b  = (const float*)d_in[11];
    const float* dw_w   = (const float*)d_in[12];
    const float* dw_b   = (const float*)d_in[13];
    const float* fc2_w  = (const float*)d_in[14];
    const float* fc2_b  = (const float*)d_in[15];

    char* ws = (char*)d_ws;
    u16*   qkvt  = (u16*)(ws);
    u16*   projt = (u16*)(ws + 221184);
    u16*   fc1t  = (u16*)(ws + 294912);
    u16*   fc2t  = (u16*)(ws + 589824);
    u16*   dwt   = (u16*)(ws + 884736);
    u16*   r1    = (u16*)(ws + 1160192);      // xw / attnb / h2 (38,535,168 B)
    u16*   qkvb  = (u16*)(ws + 39695360LL);   // 115,605,504 B
    u16*   x2b   = (u16*)(ws + 39695360LL);   // bf16 residual (aliases dead qkvb)
    u16*   hid_c = (u16*)(ws + 78230528LL);   // per-batch [50176][768] bf16
    float* bmat  = (float*)(ws + 155300864LL);// [6][112][112] f32, dead before gelu
    u16*   gelu_c= (u16*)(ws + 155300864LL);  // per-batch [50176][768] bf16

    prep_weights<<<dim3(1809), dim3(256), 0, stream>>>(qkv_w, proj_w, fc1_w, fc2_w, dw_w,
                                                       qkvt, projt, fc1t, fc2t, dwt);
    biasmat_kernel<<<dim3(294), dim3(256), 0, stream>>>(btab, bmat);
    // LN1 (window-permuted) -> r1
    ln_kernel<true, false><<<dim3(25088), dim3(256), 0, stream>>>(x, n1g, n1b, r1);
    // QKV GEMM: r1 -> qkvb
    gemm_bt<0><<<dim3(784, 9), dim3(256), 0, stream>>>(r1, qkvt, qkv_b, 192, 576,
                                                       qkvb, nullptr, nullptr, nullptr, 0);
    // MFMA attention: qkvb -> r1 (attnb)
    attn_mfma_kernel<<<dim3(1024, 6), dim3(64), 0, stream>>>(qkvb, bmat, r1);
    // Proj GEMM + window-reverse + residual: r1, x -> x2b (bf16)
    gemm_bt<1><<<dim3(784, 3), dim3(256), 0, stream>>>(r1, projt, proj_b, 192, 192,
                                                       nullptr, x, x2b, nullptr, 0);
    // LN2: x2b -> r1 (h2)
    ln_kernel<false, true><<<dim3(25088), dim3(256), 0, stream>>>(x2b, n2g, n2b, r1);
    // FFN chunked over batch
    for (int b = 0; b < 2; b++) {
        const u16* h2c = r1 + (size_t)b * M_HALF * DIMC;
        gemm_bt<0><<<dim3(392, 12), dim3(256), 0, stream>>>(h2c, fc1t, fc1_b, 192, 768,
                                                            hid_c, nullptr, nullptr, nullptr, 0);
        dwconv_gelu_kernel<<<dim3(18816), dim3(256), 0, stream>>>(hid_c, dwt, dw_b, gelu_c);
        gemm_bt<2><<<dim3(392, 3), dim3(256), 0, stream>>>(gelu_c, fc2t, fc2_b, 768, 192,
                                                           nullptr, nullptr, x2b, (float*)d_out,
                                                           b * M_HALF);
    }
}

// Round 5
// 893.244 us; speedup vs baseline: 1.3608x; 1.0078x over previous
//
#include <hip/hip_runtime.h>
#include <hip/hip_bf16.h>

typedef unsigned short u16;
typedef unsigned int   u32;
typedef __bf16 bf16x8 __attribute__((ext_vector_type(8)));
typedef float  f32x4  __attribute__((ext_vector_type(4)));

// Problem constants
#define M_TOK 100352      // B*N = 2*16*56*56 tokens
#define M_HALF 50176      // tokens per batch
#define DIMC  192
#define HIDC  768
#define SCALE_F 0.17677669529663688f

__device__ __forceinline__ float b2f(u16 u) {
    u32 x = ((u32)u) << 16; float f; __builtin_memcpy(&f, &x, 4); return f;
}
__device__ __forceinline__ u16 f2b(float f) {
    u32 x; __builtin_memcpy(&x, &f, 4);
    x = x + 0x7FFFu + ((x >> 16) & 1u);   // round-to-nearest-even
    return (u16)(x >> 16);
}

// ---------------------------------------------------------------------------
// Weight prep: fp32 -> bf16, transpose to [N][K] for GEMM B-operand;
// depthwise weights [768][27] -> [27][768].
// ---------------------------------------------------------------------------
__global__ __launch_bounds__(256) void prep_weights(
    const float* __restrict__ qkv_w, const float* __restrict__ proj_w,
    const float* __restrict__ fc1_w, const float* __restrict__ fc2_w,
    const float* __restrict__ dw_w,
    u16* __restrict__ qkvt, u16* __restrict__ projt, u16* __restrict__ fc1t,
    u16* __restrict__ fc2t, u16* __restrict__ dwt)
{
    int id = blockIdx.x * 256 + threadIdx.x;
    if (id < 110592)      { int n = id / 192, k = id % 192;                 qkvt[id] = f2b(qkv_w[k * 576 + n]); }
    else if (id < 147456) { int e = id - 110592, n = e / 192, k = e % 192;  projt[e] = f2b(proj_w[k * 192 + n]); }
    else if (id < 294912) { int e = id - 147456, n = e / 192, k = e % 192;  fc1t[e]  = f2b(fc1_w[k * 768 + n]); }
    else if (id < 442368) { int e = id - 294912, n = e / 768, k = e % 768;  fc2t[e]  = f2b(fc2_w[k * 192 + n]); }
    else if (id < 463104) { int e = id - 442368, t = e / 768, c = e % 768;  dwt[e]   = f2b(dw_w[c * 27 + t]); }
}

// ---------------------------------------------------------------------------
// Relative-position bias matrix, PADDED: bmat[head][112][112] f32.
// ---------------------------------------------------------------------------
__global__ __launch_bounds__(256) void biasmat_kernel(
    const float* __restrict__ btab, float* __restrict__ bmat)
{
    int id = blockIdx.x * 256 + threadIdx.x;
    if (id >= 6 * 112 * 112) return;
    int h = id / 12544, rem = id % 12544, i = rem / 112, j = rem % 112;
    float v;
    if (j >= 98)      v = -1e30f;
    else if (i >= 98) v = 0.0f;
    else {
        int di = i / 49, hi = (i / 7) % 7, wi = i % 7;
        int dj = j / 49, hj = (j / 7) % 7, wj = j % 7;
        int idx = (di - dj + 1) * 169 + (hi - hj + 6) * 13 + (wi - wj + 6);
        v = btab[idx * 6 + h];
    }
    bmat[id] = v;
}

// ---------------------------------------------------------------------------
// LayerNorm over 192; one wave per row. PERM=true writes window-major order.
// ---------------------------------------------------------------------------
template<bool PERM, bool BF_IN>
__global__ __launch_bounds__(256) void ln_kernel(
    const void* __restrict__ xin, const float* __restrict__ g,
    const float* __restrict__ bb, u16* __restrict__ out)
{
    int row  = blockIdx.x * 4 + (threadIdx.x >> 6);
    int lane = threadIdx.x & 63;
    float v0, v1, v2;
    if (BF_IN) {
        const u16* xr = (const u16*)xin + (size_t)row * DIMC;
        v0 = b2f(xr[lane]); v1 = b2f(xr[lane + 64]); v2 = b2f(xr[lane + 128]);
    } else {
        const float* xr = (const float*)xin + (size_t)row * DIMC;
        v0 = xr[lane]; v1 = xr[lane + 64]; v2 = xr[lane + 128];
    }
    float s  = v0 + v1 + v2;
    float s2 = v0 * v0 + v1 * v1 + v2 * v2;
    #pragma unroll
    for (int m = 1; m < 64; m <<= 1) { s += __shfl_xor(s, m); s2 += __shfl_xor(s2, m); }
    float mu = s * (1.0f / 192.0f);
    float rs = rsqrtf(s2 * (1.0f / 192.0f) - mu * mu + 1e-5f);
    size_t ob;
    if (PERM) {
        int b = row / 50176, r = row % 50176;
        int d = r / 3136, r2 = r % 3136, h = r2 / 56, w = r2 % 56;
        int widx = ((b * 8 + (d >> 1)) * 8 + h / 7) * 8 + w / 7;
        int tok  = (d & 1) * 49 + (h % 7) * 7 + (w % 7);
        ob = ((size_t)widx * 98 + tok) * DIMC;
    } else {
        ob = (size_t)row * DIMC;
    }
    out[ob + lane]       = f2b((v0 - mu) * rs * g[lane]       + bb[lane]);
    out[ob + lane + 64]  = f2b((v1 - mu) * rs * g[lane + 64]  + bb[lane + 64]);
    out[ob + lane + 128] = f2b((v2 - mu) * rs * g[lane + 128] + bb[lane + 128]);
}

// ---------------------------------------------------------------------------
// bf16 MFMA GEMM: C[M,N] = A[M,K] * Bt[N,K]^T + bias  (unchanged, verified)
// ---------------------------------------------------------------------------
template<int EPI>
__global__ __launch_bounds__(256) void gemm_bt(
    const u16* __restrict__ A, const u16* __restrict__ Bt,
    const float* __restrict__ bias, int K, int N,
    u16* __restrict__ outb, const float* __restrict__ xres,
    u16* __restrict__ x2b, float* __restrict__ outf, int mofs)
{
    __shared__ __align__(16) u16 Alds[128 * 32];
    __shared__ __align__(16) u16 Blds[64 * 32];
    int m0 = blockIdx.x * 128;
    int n0 = blockIdx.y * 64;
    int t  = threadIdx.x;
    int ar = t >> 2, ac = (t & 3) * 8;
    int lane = t & 63, wid = t >> 6;
    int wm = wid >> 1, wn = wid & 1;
    int lrow = lane & 15, lko = (lane >> 4) * 8;
    const u16* Ab  = A  + (size_t)(m0 + ar) * K + ac;
    const u16* Ab2 = Ab + (size_t)64 * K;
    const u16* Bb  = Bt + (size_t)(n0 + ar) * K + ac;
    f32x4 acc[4][2] = {};
    for (int kt = 0; kt < K; kt += 32) {
        uint4 a0 = *(const uint4*)(Ab  + kt);
        uint4 a1 = *(const uint4*)(Ab2 + kt);
        uint4 b0 = *(const uint4*)(Bb  + kt);
        __syncthreads();
        ((uint4*)Alds)[t]       = a0;
        ((uint4*)Alds)[256 + t] = a1;
        ((uint4*)Blds)[t]       = b0;
        __syncthreads();
        bf16x8 af[4], bfr[2];
        #pragma unroll
        for (int mi = 0; mi < 4; mi++)
            af[mi] = *(const bf16x8*)&Alds[(wm * 64 + mi * 16 + lrow) * 32 + lko];
        #pragma unroll
        for (int ni = 0; ni < 2; ni++)
            bfr[ni] = *(const bf16x8*)&Blds[(wn * 32 + ni * 16 + lrow) * 32 + lko];
        #pragma unroll
        for (int mi = 0; mi < 4; mi++)
            #pragma unroll
            for (int ni = 0; ni < 2; ni++)
                acc[mi][ni] = __builtin_amdgcn_mfma_f32_16x16x32_bf16(af[mi], bfr[ni], acc[mi][ni], 0, 0, 0);
    }
    int r0 = (lane >> 4) * 4, cl = lane & 15;
    #pragma unroll
    for (int ni = 0; ni < 2; ni++) {
        int col = n0 + wn * 32 + ni * 16 + cl;
        float bv = bias[col];
        #pragma unroll
        for (int mi = 0; mi < 4; mi++) {
            #pragma unroll
            for (int r = 0; r < 4; r++) {
                int row = m0 + wm * 64 + mi * 16 + r0 + r;
                float v = acc[mi][ni][r] + bv;
                if (EPI == 0) {
                    outb[(size_t)row * N + col] = f2b(v);
                } else if (EPI == 1) {
                    int widx = row / 98, tok = row % 98;
                    int b = widx >> 9, rem = widx & 511;
                    int bd = rem >> 6, bh = (rem >> 3) & 7, bw = rem & 7;
                    int td = tok / 49, rr = tok % 49, th = rr / 7, tw = rr % 7;
                    int d = bd * 2 + td, h = bh * 7 + th, w = bw * 7 + tw;
                    size_t gg = ((size_t)b * 50176 + (d * 56 + h) * 56 + w) * (size_t)N + col;
                    x2b[gg] = f2b(xres[gg] + 0.5f * v);
                } else {
                    size_t gg = (size_t)(row + mofs) * N + col;
                    outf[gg] = b2f(x2b[gg]) + 0.5f * v;
                }
            }
        }
    }
}

// ---------------------------------------------------------------------------
// MFMA window attention: 1 wave per (window, head). 98 tokens padded to 112.
// ---------------------------------------------------------------------------
__global__ __launch_bounds__(64) void attn_mfma_kernel(
    const u16* __restrict__ qkv, const float* __restrict__ bmat,
    u16* __restrict__ outb)
{
    __shared__ __align__(16) u16 Klds[112 * 40];
    __shared__ __align__(16) u16 Vt[32 * 136];
    __shared__ __align__(16) u16 Plds[16 * 136];
    int widx = blockIdx.x, head = blockIdx.y;
    int l = threadIdx.x;
    int c = l & 15, g = l >> 4;
    size_t wbase = (size_t)widx * (98 * 576) + head * 32;

    for (int e = l; e < 448; e += 64) {
        int rr = e >> 2, seg = (e & 3) * 8;
        uint4 kr = {0, 0, 0, 0}, vr = {0, 0, 0, 0};
        if (rr < 98) {
            kr = *(const uint4*)(qkv + wbase + (size_t)rr * 576 + 192 + seg);
            vr = *(const uint4*)(qkv + wbase + (size_t)rr * 576 + 384 + seg);
        }
        *(uint4*)&Klds[rr * 40 + seg] = kr;
        int sw = ((seg >> 3) & 3) << 4;
        int pc = rr ^ sw;
        const u16* vp = (const u16*)&vr;
        #pragma unroll
        for (int u = 0; u < 8; u++)
            Vt[(seg + u) * 136 + pc] = vp[u];
    }
    {
        int d = l >> 1, half = l & 1;
        int sw = ((d >> 3) & 3) << 4;
        uint4 z = {0, 0, 0, 0};
        *(uint4*)&Vt[d * 136 + ((112 + 8 * half) ^ sw)] = z;
        if (l < 32) {
            int i = l >> 1; half = l & 1;
            int swp = ((i >> 2) & 3) << 4;
            *(uint4*)&Plds[i * 136 + ((112 + 8 * half) ^ swp)] = z;
        }
    }

    for (int it = 0; it < 7; ++it) {
        int qtok = 16 * it + c; if (qtok > 97) qtok = 97;
        bf16x8 qf = *(const bf16x8*)(qkv + wbase + (size_t)qtok * 576 + g * 8);
        f32x4 s[7];
        f32x4 z = {};
        #pragma unroll
        for (int jt = 0; jt < 7; ++jt) {
            bf16x8 kf = *(const bf16x8*)&Klds[(16 * jt + c) * 40 + g * 8];
            s[jt] = __builtin_amdgcn_mfma_f32_16x16x32_bf16(qf, kf, z, 0, 0, 0);
        }
        const float* bb = bmat + ((size_t)head * 112 + 16 * it + 4 * g) * 112 + c;
        float sm[4];
        #pragma unroll
        for (int r = 0; r < 4; ++r) {
            float m = -1e30f;
            #pragma unroll
            for (int jt = 0; jt < 7; ++jt) {
                float v = s[jt][r] * SCALE_F + bb[r * 112 + 16 * jt];
                s[jt][r] = v;
                m = fmaxf(m, v);
            }
            m = fmaxf(m, __shfl_xor(m, 1)); m = fmaxf(m, __shfl_xor(m, 2));
            m = fmaxf(m, __shfl_xor(m, 4)); m = fmaxf(m, __shfl_xor(m, 8));
            float su = 0.f;
            #pragma unroll
            for (int jt = 0; jt < 7; ++jt) {
                float p = __expf(s[jt][r] - m);
                s[jt][r] = p;
                su += p;
            }
            su += __shfl_xor(su, 1); su += __shfl_xor(su, 2);
            su += __shfl_xor(su, 4); su += __shfl_xor(su, 8);
            sm[r] = su;
        }
        #pragma unroll
        for (int r = 0; r < 4; ++r) {
            int prow = 4 * g + r;
            int swp = ((prow >> 2) & 3) << 4;
            #pragma unroll
            for (int jt = 0; jt < 7; ++jt)
                Plds[prow * 136 + ((16 * jt + c) ^ swp)] = f2b(s[jt][r]);
        }
        bf16x8 pa[4];
        int swr = ((c >> 2) & 3) << 4;
        #pragma unroll
        for (int ks = 0; ks < 4; ++ks)
            pa[ks] = *(const bf16x8*)&Plds[c * 136 + ((32 * ks + 8 * g) ^ swr)];
        #pragma unroll
        for (int dt = 0; dt < 2; ++dt) {
            f32x4 o = {};
            int vrow = 16 * dt + c;
            int swv = ((vrow >> 3) & 3) << 4;
            #pragma unroll
            for (int ks = 0; ks < 4; ++ks) {
                bf16x8 vb = *(const bf16x8*)&Vt[vrow * 136 + ((32 * ks + 8 * g) ^ swv)];
                o = __builtin_amdgcn_mfma_f32_16x16x32_bf16(pa[ks], vb, o, 0, 0, 0);
            }
            #pragma unroll
            for (int r = 0; r < 4; ++r) {
                int row = 16 * it + 4 * g + r;
                if (row < 98)
                    outb[((size_t)widx * 98 + row) * DIMC + head * 32 + 16 * dt + c]
                        = f2b(o[r] / sm[r]);
            }
        }
    }
}

// ---------------------------------------------------------------------------
// Depthwise 3x3x3 conv + exact GELU, register-blocked: each thread computes
// 4 outputs along w for 8 channels. Weight loads = minimal 27/thread
// (tap = iz*9+iy*3+dx); input w-overlap kept in registers (6 loads / 4 outs).
// ---------------------------------------------------------------------------
__global__ __launch_bounds__(256) void dwconv_gelu_kernel(
    const u16* __restrict__ hid, const u16* __restrict__ dwt,
    const float* __restrict__ dwb, u16* __restrict__ outb)
{
    int gid = blockIdx.x * 256 + threadIdx.x;
    int cg = gid % 96;
    int t  = gid / 96;
    int w0 = (t % 14) * 4;
    t /= 14;
    int h = t % 56;
    int d = t / 56;                 // 0..15
    int c0 = cg * 8;

    float acc[4][8];
    {
        float4 bv0 = *(const float4*)(dwb + c0);
        float4 bv1 = *(const float4*)(dwb + c0 + 4);
        #pragma unroll
        for (int wi = 0; wi < 4; ++wi) {
            acc[wi][0] = bv0.x; acc[wi][1] = bv0.y; acc[wi][2] = bv0.z; acc[wi][3] = bv0.w;
            acc[wi][4] = bv1.x; acc[wi][5] = bv1.y; acc[wi][6] = bv1.z; acc[wi][7] = bv1.w;
        }
    }

    #pragma unroll
    for (int iz = 0; iz < 3; ++iz) {
        int zz = d - 1 + iz;
        if ((unsigned)zz >= 16u) continue;
        #pragma unroll
        for (int iy = 0; iy < 3; ++iy) {
            int yy = h - 1 + iy;
            if ((unsigned)yy >= 56u) continue;
            // load 6 input positions xx = w0-1 .. w0+4 (zero-filled OOB)
            float in6[6][8];
            const u16* rp = hid + ((size_t)(zz * 56 + yy) * 56 + w0 - 1) * HIDC + c0;
            #pragma unroll
            for (int ix = 0; ix < 6; ++ix) {
                uint4 iv = {0, 0, 0, 0};
                if ((unsigned)(w0 - 1 + ix) < 56u)
                    iv = *(const uint4*)(rp + (size_t)ix * HIDC);
                const u16* ip = (const u16*)&iv;
                #pragma unroll
                for (int u = 0; u < 8; ++u) in6[ix][u] = b2f(ip[u]);
            }
            // 3 weight taps for this (iz,iy); each used by all 4 outputs
            #pragma unroll
            for (int dx = 0; dx < 3; ++dx) {
                uint4 wv = *(const uint4*)(dwt + (size_t)(iz * 9 + iy * 3 + dx) * HIDC + c0);
                const u16* wq = (const u16*)&wv;
                float wf[8];
                #pragma unroll
                for (int u = 0; u < 8; ++u) wf[u] = b2f(wq[u]);
                #pragma unroll
                for (int wi = 0; wi < 4; ++wi)
                    #pragma unroll
                    for (int u = 0; u < 8; ++u)
                        acc[wi][u] += in6[wi + dx][u] * wf[u];
            }
        }
    }

    size_t tok0 = (size_t)(d * 56 + h) * 56 + w0;
    #pragma unroll
    for (int wi = 0; wi < 4; ++wi) {
        u16 res[8];
        #pragma unroll
        for (int u = 0; u < 8; ++u) {
            float a = acc[wi][u];
            res[u] = f2b(0.5f * a * (1.0f + erff(a * 0.70710678118654752f)));
        }
        uint4 ov;
        u32* op = (u32*)&ov;
        op[0] = (u32)res[0] | ((u32)res[1] << 16);
        op[1] = (u32)res[2] | ((u32)res[3] << 16);
        op[2] = (u32)res[4] | ((u32)res[5] << 16);
        op[3] = (u32)res[6] | ((u32)res[7] << 16);
        *(uint4*)(outb + (tok0 + wi) * HIDC + c0) = ov;
    }
}

// ---------------------------------------------------------------------------
// Orchestration (workspace layout unchanged from round 3).
// ---------------------------------------------------------------------------
extern "C" void kernel_launch(void* const* d_in, const int* in_sizes, int n_in,
                              void* d_out, int out_size, void* d_ws, size_t ws_size,
                              hipStream_t stream)
{
    const float* x      = (const float*)d_in[0];
    const float* n1g    = (const float*)d_in[1];
    const float* n1b    = (const float*)d_in[2];
    const float* qkv_w  = (const float*)d_in[3];
    const float* qkv_b  = (const float*)d_in[4];
    const float* btab   = (const float*)d_in[5];
    const float* proj_w = (const float*)d_in[6];
    const float* proj_b = (const float*)d_in[7];
    const float* n2g    = (const float*)d_in[8];
    const float* n2b    = (const float*)d_in[9];
    const float* fc1_w  = (const float*)d_in[10];
    const float* fc1_b  = (const float*)d_in[11];
    const float* dw_w   = (const float*)d_in[12];
    const float* dw_b   = (const float*)d_in[13];
    const float* fc2_w  = (const float*)d_in[14];
    const float* fc2_b  = (const float*)d_in[15];

    char* ws = (char*)d_ws;
    u16*   qkvt  = (u16*)(ws);
    u16*   projt = (u16*)(ws + 221184);
    u16*   fc1t  = (u16*)(ws + 294912);
    u16*   fc2t  = (u16*)(ws + 589824);
    u16*   dwt   = (u16*)(ws + 884736);
    u16*   r1    = (u16*)(ws + 1160192);      // xw / attnb / h2 (38,535,168 B)
    u16*   qkvb  = (u16*)(ws + 39695360LL);   // 115,605,504 B
    u16*   x2b   = (u16*)(ws + 39695360LL);   // bf16 residual (aliases dead qkvb)
    u16*   hid_c = (u16*)(ws + 78230528LL);   // per-batch [50176][768] bf16
    float* bmat  = (float*)(ws + 155300864LL);// [6][112][112] f32, dead before gelu
    u16*   gelu_c= (u16*)(ws + 155300864LL);  // per-batch [50176][768] bf16

    prep_weights<<<dim3(1809), dim3(256), 0, stream>>>(qkv_w, proj_w, fc1_w, fc2_w, dw_w,
                                                       qkvt, projt, fc1t, fc2t, dwt);
    biasmat_kernel<<<dim3(294), dim3(256), 0, stream>>>(btab, bmat);
    ln_kernel<true, false><<<dim3(25088), dim3(256), 0, stream>>>(x, n1g, n1b, r1);
    gemm_bt<0><<<dim3(784, 9), dim3(256), 0, stream>>>(r1, qkvt, qkv_b, 192, 576,
                                                       qkvb, nullptr, nullptr, nullptr, 0);
    attn_mfma_kernel<<<dim3(1024, 6), dim3(64), 0, stream>>>(qkvb, bmat, r1);
    gemm_bt<1><<<dim3(784, 3), dim3(256), 0, stream>>>(r1, projt, proj_b, 192, 192,
                                                       nullptr, x, x2b, nullptr, 0);
    ln_kernel<false, true><<<dim3(25088), dim3(256), 0, stream>>>(x2b, n2g, n2b, r1);
    for (int b = 0; b < 2; b++) {
        const u16* h2c = r1 + (size_t)b * M_HALF * DIMC;
        gemm_bt<0><<<dim3(392, 12), dim3(256), 0, stream>>>(h2c, fc1t, fc1_b, 192, 768,
                                                            hid_c, nullptr, nullptr, nullptr, 0);
        dwconv_gelu_kernel<<<dim3(4704), dim3(256), 0, stream>>>(hid_c, dwt, dw_b, gelu_c);
        gemm_bt<2><<<dim3(392, 3), dim3(256), 0, stream>>>(gelu_c, fc2t, fc2_b, 768, 192,
                                                           nullptr, nullptr, x2b, (float*)d_out,
                                                           b * M_HALF);
    }
}

// Round 6
// 837.751 us; speedup vs baseline: 1.4509x; 1.0662x over previous
//
#include <hip/hip_runtime.h>
#include <hip/hip_bf16.h>

typedef unsigned short u16;
typedef unsigned int   u32;
typedef __bf16 bf16x8 __attribute__((ext_vector_type(8)));
typedef float  f32x4  __attribute__((ext_vector_type(4)));
typedef float  f32x2  __attribute__((ext_vector_type(2)));

// Problem constants
#define M_TOK 100352      // B*N = 2*16*56*56 tokens
#define M_HALF 50176      // tokens per batch
#define DIMC  192
#define HIDC  768
#define SCALE_F 0.17677669529663688f

__device__ __forceinline__ float b2f(u16 u) {
    u32 x = ((u32)u) << 16; float f; __builtin_memcpy(&f, &x, 4); return f;
}
__device__ __forceinline__ u16 f2b(float f) {
    u32 x; __builtin_memcpy(&x, &f, 4);
    x = x + 0x7FFFu + ((x >> 16) & 1u);   // round-to-nearest-even
    return (u16)(x >> 16);
}
__device__ __forceinline__ float lo2f(u32 w) {  // low u16 -> f32
    u32 x = w << 16; float f; __builtin_memcpy(&f, &x, 4); return f;
}
__device__ __forceinline__ float hi2f(u32 w) {  // high u16 -> f32
    u32 x = w & 0xFFFF0000u; float f; __builtin_memcpy(&f, &x, 4); return f;
}

// ---------------------------------------------------------------------------
// Weight prep: fp32 -> bf16 transposed [N][K] for GEMM B-operands;
// depthwise weights [768][27] -> f32 [27][768] (no converts in dwconv).
// ---------------------------------------------------------------------------
__global__ __launch_bounds__(256) void prep_weights(
    const float* __restrict__ qkv_w, const float* __restrict__ proj_w,
    const float* __restrict__ fc1_w, const float* __restrict__ fc2_w,
    const float* __restrict__ dw_w,
    u16* __restrict__ qkvt, u16* __restrict__ projt, u16* __restrict__ fc1t,
    u16* __restrict__ fc2t, float* __restrict__ dwtf)
{
    int id = blockIdx.x * 256 + threadIdx.x;
    if (id < 110592)      { int n = id / 192, k = id % 192;                 qkvt[id] = f2b(qkv_w[k * 576 + n]); }
    else if (id < 147456) { int e = id - 110592, n = e / 192, k = e % 192;  projt[e] = f2b(proj_w[k * 192 + n]); }
    else if (id < 294912) { int e = id - 147456, n = e / 192, k = e % 192;  fc1t[e]  = f2b(fc1_w[k * 768 + n]); }
    else if (id < 442368) { int e = id - 294912, n = e / 768, k = e % 768;  fc2t[e]  = f2b(fc2_w[k * 192 + n]); }
    else if (id < 463104) { int e = id - 442368, t = e / 768, c = e % 768;  dwtf[e]  = dw_w[c * 27 + t]; }
}

// ---------------------------------------------------------------------------
// Relative-position bias matrix, PADDED: bmat[head][112][112] f32.
// ---------------------------------------------------------------------------
__global__ __launch_bounds__(256) void biasmat_kernel(
    const float* __restrict__ btab, float* __restrict__ bmat)
{
    int id = blockIdx.x * 256 + threadIdx.x;
    if (id >= 6 * 112 * 112) return;
    int h = id / 12544, rem = id % 12544, i = rem / 112, j = rem % 112;
    float v;
    if (j >= 98)      v = -1e30f;
    else if (i >= 98) v = 0.0f;
    else {
        int di = i / 49, hi = (i / 7) % 7, wi = i % 7;
        int dj = j / 49, hj = (j / 7) % 7, wj = j % 7;
        int idx = (di - dj + 1) * 169 + (hi - hj + 6) * 13 + (wi - wj + 6);
        v = btab[idx * 6 + h];
    }
    bmat[id] = v;
}

// ---------------------------------------------------------------------------
// LayerNorm over 192; one wave per row. PERM=true writes window-major order.
// ---------------------------------------------------------------------------
template<bool PERM, bool BF_IN>
__global__ __launch_bounds__(256) void ln_kernel(
    const void* __restrict__ xin, const float* __restrict__ g,
    const float* __restrict__ bb, u16* __restrict__ out)
{
    int row  = blockIdx.x * 4 + (threadIdx.x >> 6);
    int lane = threadIdx.x & 63;
    float v0, v1, v2;
    if (BF_IN) {
        const u16* xr = (const u16*)xin + (size_t)row * DIMC;
        v0 = b2f(xr[lane]); v1 = b2f(xr[lane + 64]); v2 = b2f(xr[lane + 128]);
    } else {
        const float* xr = (const float*)xin + (size_t)row * DIMC;
        v0 = xr[lane]; v1 = xr[lane + 64]; v2 = xr[lane + 128];
    }
    float s  = v0 + v1 + v2;
    float s2 = v0 * v0 + v1 * v1 + v2 * v2;
    #pragma unroll
    for (int m = 1; m < 64; m <<= 1) { s += __shfl_xor(s, m); s2 += __shfl_xor(s2, m); }
    float mu = s * (1.0f / 192.0f);
    float rs = rsqrtf(s2 * (1.0f / 192.0f) - mu * mu + 1e-5f);
    size_t ob;
    if (PERM) {
        int b = row / 50176, r = row % 50176;
        int d = r / 3136, r2 = r % 3136, h = r2 / 56, w = r2 % 56;
        int widx = ((b * 8 + (d >> 1)) * 8 + h / 7) * 8 + w / 7;
        int tok  = (d & 1) * 49 + (h % 7) * 7 + (w % 7);
        ob = ((size_t)widx * 98 + tok) * DIMC;
    } else {
        ob = (size_t)row * DIMC;
    }
    out[ob + lane]       = f2b((v0 - mu) * rs * g[lane]       + bb[lane]);
    out[ob + lane + 64]  = f2b((v1 - mu) * rs * g[lane + 64]  + bb[lane + 64]);
    out[ob + lane + 128] = f2b((v2 - mu) * rs * g[lane + 128] + bb[lane + 128]);
}

// ---------------------------------------------------------------------------
// bf16 MFMA GEMM: C[M,N] = A[M,K] * Bt[N,K]^T + bias  (unchanged, verified)
// ---------------------------------------------------------------------------
template<int EPI>
__global__ __launch_bounds__(256) void gemm_bt(
    const u16* __restrict__ A, const u16* __restrict__ Bt,
    const float* __restrict__ bias, int K, int N,
    u16* __restrict__ outb, const float* __restrict__ xres,
    u16* __restrict__ x2b, float* __restrict__ outf, int mofs)
{
    __shared__ __align__(16) u16 Alds[128 * 32];
    __shared__ __align__(16) u16 Blds[64 * 32];
    int m0 = blockIdx.x * 128;
    int n0 = blockIdx.y * 64;
    int t  = threadIdx.x;
    int ar = t >> 2, ac = (t & 3) * 8;
    int lane = t & 63, wid = t >> 6;
    int wm = wid >> 1, wn = wid & 1;
    int lrow = lane & 15, lko = (lane >> 4) * 8;
    const u16* Ab  = A  + (size_t)(m0 + ar) * K + ac;
    const u16* Ab2 = Ab + (size_t)64 * K;
    const u16* Bb  = Bt + (size_t)(n0 + ar) * K + ac;
    f32x4 acc[4][2] = {};
    for (int kt = 0; kt < K; kt += 32) {
        uint4 a0 = *(const uint4*)(Ab  + kt);
        uint4 a1 = *(const uint4*)(Ab2 + kt);
        uint4 b0 = *(const uint4*)(Bb  + kt);
        __syncthreads();
        ((uint4*)Alds)[t]       = a0;
        ((uint4*)Alds)[256 + t] = a1;
        ((uint4*)Blds)[t]       = b0;
        __syncthreads();
        bf16x8 af[4], bfr[2];
        #pragma unroll
        for (int mi = 0; mi < 4; mi++)
            af[mi] = *(const bf16x8*)&Alds[(wm * 64 + mi * 16 + lrow) * 32 + lko];
        #pragma unroll
        for (int ni = 0; ni < 2; ni++)
            bfr[ni] = *(const bf16x8*)&Blds[(wn * 32 + ni * 16 + lrow) * 32 + lko];
        #pragma unroll
        for (int mi = 0; mi < 4; mi++)
            #pragma unroll
            for (int ni = 0; ni < 2; ni++)
                acc[mi][ni] = __builtin_amdgcn_mfma_f32_16x16x32_bf16(af[mi], bfr[ni], acc[mi][ni], 0, 0, 0);
    }
    int r0 = (lane >> 4) * 4, cl = lane & 15;
    #pragma unroll
    for (int ni = 0; ni < 2; ni++) {
        int col = n0 + wn * 32 + ni * 16 + cl;
        float bv = bias[col];
        #pragma unroll
        for (int mi = 0; mi < 4; mi++) {
            #pragma unroll
            for (int r = 0; r < 4; r++) {
                int row = m0 + wm * 64 + mi * 16 + r0 + r;
                float v = acc[mi][ni][r] + bv;
                if (EPI == 0) {
                    outb[(size_t)row * N + col] = f2b(v);
                } else if (EPI == 1) {
                    int widx = row / 98, tok = row % 98;
                    int b = widx >> 9, rem = widx & 511;
                    int bd = rem >> 6, bh = (rem >> 3) & 7, bw = rem & 7;
                    int td = tok / 49, rr = tok % 49, th = rr / 7, tw = rr % 7;
                    int d = bd * 2 + td, h = bh * 7 + th, w = bw * 7 + tw;
                    size_t gg = ((size_t)b * 50176 + (d * 56 + h) * 56 + w) * (size_t)N + col;
                    x2b[gg] = f2b(xres[gg] + 0.5f * v);
                } else {
                    size_t gg = (size_t)(row + mofs) * N + col;
                    outf[gg] = b2f(x2b[gg]) + 0.5f * v;
                }
            }
        }
    }
}

// ---------------------------------------------------------------------------
// MFMA window attention: 1 wave per (window, head). 98 tokens padded to 112.
// ---------------------------------------------------------------------------
__global__ __launch_bounds__(64) void attn_mfma_kernel(
    const u16* __restrict__ qkv, const float* __restrict__ bmat,
    u16* __restrict__ outb)
{
    __shared__ __align__(16) u16 Klds[112 * 40];
    __shared__ __align__(16) u16 Vt[32 * 136];
    __shared__ __align__(16) u16 Plds[16 * 136];
    int widx = blockIdx.x, head = blockIdx.y;
    int l = threadIdx.x;
    int c = l & 15, g = l >> 4;
    size_t wbase = (size_t)widx * (98 * 576) + head * 32;

    for (int e = l; e < 448; e += 64) {
        int rr = e >> 2, seg = (e & 3) * 8;
        uint4 kr = {0, 0, 0, 0}, vr = {0, 0, 0, 0};
        if (rr < 98) {
            kr = *(const uint4*)(qkv + wbase + (size_t)rr * 576 + 192 + seg);
            vr = *(const uint4*)(qkv + wbase + (size_t)rr * 576 + 384 + seg);
        }
        *(uint4*)&Klds[rr * 40 + seg] = kr;
        int sw = ((seg >> 3) & 3) << 4;
        int pc = rr ^ sw;
        const u16* vp = (const u16*)&vr;
        #pragma unroll
        for (int u = 0; u < 8; u++)
            Vt[(seg + u) * 136 + pc] = vp[u];
    }
    {
        int d = l >> 1, half = l & 1;
        int sw = ((d >> 3) & 3) << 4;
        uint4 z = {0, 0, 0, 0};
        *(uint4*)&Vt[d * 136 + ((112 + 8 * half) ^ sw)] = z;
        if (l < 32) {
            int i = l >> 1; half = l & 1;
            int swp = ((i >> 2) & 3) << 4;
            *(uint4*)&Plds[i * 136 + ((112 + 8 * half) ^ swp)] = z;
        }
    }

    for (int it = 0; it < 7; ++it) {
        int qtok = 16 * it + c; if (qtok > 97) qtok = 97;
        bf16x8 qf = *(const bf16x8*)(qkv + wbase + (size_t)qtok * 576 + g * 8);
        f32x4 s[7];
        f32x4 z = {};
        #pragma unroll
        for (int jt = 0; jt < 7; ++jt) {
            bf16x8 kf = *(const bf16x8*)&Klds[(16 * jt + c) * 40 + g * 8];
            s[jt] = __builtin_amdgcn_mfma_f32_16x16x32_bf16(qf, kf, z, 0, 0, 0);
        }
        const float* bb = bmat + ((size_t)head * 112 + 16 * it + 4 * g) * 112 + c;
        float sm[4];
        #pragma unroll
        for (int r = 0; r < 4; ++r) {
            float m = -1e30f;
            #pragma unroll
            for (int jt = 0; jt < 7; ++jt) {
                float v = s[jt][r] * SCALE_F + bb[r * 112 + 16 * jt];
                s[jt][r] = v;
                m = fmaxf(m, v);
            }
            m = fmaxf(m, __shfl_xor(m, 1)); m = fmaxf(m, __shfl_xor(m, 2));
            m = fmaxf(m, __shfl_xor(m, 4)); m = fmaxf(m, __shfl_xor(m, 8));
            float su = 0.f;
            #pragma unroll
            for (int jt = 0; jt < 7; ++jt) {
                float p = __expf(s[jt][r] - m);
                s[jt][r] = p;
                su += p;
            }
            su += __shfl_xor(su, 1); su += __shfl_xor(su, 2);
            su += __shfl_xor(su, 4); su += __shfl_xor(su, 8);
            sm[r] = su;
        }
        #pragma unroll
        for (int r = 0; r < 4; ++r) {
            int prow = 4 * g + r;
            int swp = ((prow >> 2) & 3) << 4;
            #pragma unroll
            for (int jt = 0; jt < 7; ++jt)
                Plds[prow * 136 + ((16 * jt + c) ^ swp)] = f2b(s[jt][r]);
        }
        bf16x8 pa[4];
        int swr = ((c >> 2) & 3) << 4;
        #pragma unroll
        for (int ks = 0; ks < 4; ++ks)
            pa[ks] = *(const bf16x8*)&Plds[c * 136 + ((32 * ks + 8 * g) ^ swr)];
        #pragma unroll
        for (int dt = 0; dt < 2; ++dt) {
            f32x4 o = {};
            int vrow = 16 * dt + c;
            int swv = ((vrow >> 3) & 3) << 4;
            #pragma unroll
            for (int ks = 0; ks < 4; ++ks) {
                bf16x8 vb = *(const bf16x8*)&Vt[vrow * 136 + ((32 * ks + 8 * g) ^ swv)];
                o = __builtin_amdgcn_mfma_f32_16x16x32_bf16(pa[ks], vb, o, 0, 0, 0);
            }
            #pragma unroll
            for (int r = 0; r < 4; ++r) {
                int row = 16 * it + 4 * g + r;
                if (row < 98)
                    outb[((size_t)widx * 98 + row) * DIMC + head * 32 + 16 * dt + c]
                        = f2b(o[r] / sm[r]);
            }
        }
    }
}

// ---------------------------------------------------------------------------
// Depthwise 3x3x3 conv + sigmoid-form GELU.
// Thread = 2 outputs along w x 8 channels. d-fastest block mapping so the 16
// d-slices of a (h,w) column are dispatch-adjacent -> z-tap reads hit L2.
// f32 weights (zero weight converts); channel-halved inner loop + float2
// packed FMA keeps peak VGPR ~56 (< the 64-VGPR occupancy cliff).
// ---------------------------------------------------------------------------
__global__ __launch_bounds__(256, 8) void dwconv_gelu_kernel(
    const u16* __restrict__ hid, const float* __restrict__ dwtf,
    const float* __restrict__ dwb, u16* __restrict__ outb)
{
    int gid = blockIdx.x * 256 + threadIdx.x;
    int cg = gid % 96;
    int t  = gid / 96;
    int d  = t & 15;
    t >>= 4;
    int wg = t % 28;
    int h  = t / 28;                  // 0..55
    int w0 = wg * 2;
    int c0 = cg * 8;

    f32x2 acc[2][4];                  // [wi][pair] ; pairs 0,1 = ch0-3, 2,3 = ch4-7
    {
        float4 b0 = *(const float4*)(dwb + c0);
        float4 b1 = *(const float4*)(dwb + c0 + 4);
        #pragma unroll
        for (int wi = 0; wi < 2; ++wi) {
            acc[wi][0] = f32x2{b0.x, b0.y};
            acc[wi][1] = f32x2{b0.z, b0.w};
            acc[wi][2] = f32x2{b1.x, b1.y};
            acc[wi][3] = f32x2{b1.z, b1.w};
        }
    }

    #pragma unroll
    for (int iz = 0; iz < 3; ++iz) {
        int zz = d - 1 + iz;
        if ((unsigned)zz >= 16u) continue;
        #pragma unroll
        for (int iy = 0; iy < 3; ++iy) {
            int yy = h - 1 + iy;
            if ((unsigned)yy >= 56u) continue;
            // 4 input positions xx = w0-1 .. w0+2 (zero-filled OOB), raw bf16
            uint4 raw[4];
            const u16* rp = hid + ((size_t)(zz * 56 + yy) * 56 + w0 - 1) * HIDC + c0;
            #pragma unroll
            for (int ix = 0; ix < 4; ++ix) {
                uint4 iv = {0, 0, 0, 0};
                if ((unsigned)(w0 - 1 + ix) < 56u)
                    iv = *(const uint4*)(rp + (size_t)ix * HIDC);
                raw[ix] = iv;
            }
            const float* wrow = dwtf + (size_t)(iz * 9 + iy * 3) * HIDC + c0;
            #pragma unroll
            for (int hf = 0; hf < 2; ++hf) {
                // convert 4 positions x 4 channels of this half
                f32x2 inf[4][2];
                #pragma unroll
                for (int p = 0; p < 4; ++p) {
                    u32 wa = hf ? raw[p].z : raw[p].x;
                    u32 wb = hf ? raw[p].w : raw[p].y;
                    inf[p][0] = f32x2{lo2f(wa), hi2f(wa)};
                    inf[p][1] = f32x2{lo2f(wb), hi2f(wb)};
                }
                #pragma unroll
                for (int dx = 0; dx < 3; ++dx) {
                    float4 wv = *(const float4*)(wrow + dx * HIDC + hf * 4);
                    f32x2 wp0 = f32x2{wv.x, wv.y};
                    f32x2 wp1 = f32x2{wv.z, wv.w};
                    acc[0][hf * 2 + 0] += inf[dx][0] * wp0;
                    acc[0][hf * 2 + 1] += inf[dx][1] * wp1;
                    acc[1][hf * 2 + 0] += inf[dx + 1][0] * wp0;
                    acc[1][hf * 2 + 1] += inf[dx + 1][1] * wp1;
                }
            }
        }
    }

    size_t tok0 = (size_t)(d * 56 + h) * 56 + w0;
    #pragma unroll
    for (int wi = 0; wi < 2; ++wi) {
        u16 res[8];
        #pragma unroll
        for (int pr = 0; pr < 4; ++pr) {
            #pragma unroll
            for (int u = 0; u < 2; ++u) {
                float a = acc[wi][pr][u];
                // gelu(a) = a * sigmoid(2t), 2t = a*(1.5957691 + 0.0713548*a^2)
                float tt = a * (1.5957691216f + 0.0713548162f * a * a);
                float n = __expf(-tt);
                res[pr * 2 + u] = f2b(a / (1.0f + n));
            }
        }
        uint4 ov;
        u32* op = (u32*)&ov;
        op[0] = (u32)res[0] | ((u32)res[1] << 16);
        op[1] = (u32)res[2] | ((u32)res[3] << 16);
        op[2] = (u32)res[4] | ((u32)res[5] << 16);
        op[3] = (u32)res[6] | ((u32)res[7] << 16);
        *(uint4*)(outb + (tok0 + wi) * HIDC + c0) = ov;
    }
}

// ---------------------------------------------------------------------------
// Orchestration (workspace layout as round 3; dwt slot now holds f32 weights).
// ---------------------------------------------------------------------------
extern "C" void kernel_launch(void* const* d_in, const int* in_sizes, int n_in,
                              void* d_out, int out_size, void* d_ws, size_t ws_size,
                              hipStream_t stream)
{
    const float* x      = (const float*)d_in[0];
    const float* n1g    = (const float*)d_in[1];
    const float* n1b    = (const float*)d_in[2];
    const float* qkv_w  = (const float*)d_in[3];
    const float* qkv_b  = (const float*)d_in[4];
    const float* btab   = (const float*)d_in[5];
    const float* proj_w = (const float*)d_in[6];
    const float* proj_b = (const float*)d_in[7];
    const float* n2g    = (const float*)d_in[8];
    const float* n2b    = (const float*)d_in[9];
    const float* fc1_w  = (const float*)d_in[10];
    const float* fc1_b  = (const float*)d_in[11];
    const float* dw_w   = (const float*)d_in[12];
    const float* dw_b   = (const float*)d_in[13];
    const float* fc2_w  = (const float*)d_in[14];
    const float* fc2_b  = (const float*)d_in[15];

    char* ws = (char*)d_ws;
    u16*   qkvt  = (u16*)(ws);
    u16*   projt = (u16*)(ws + 221184);
    u16*   fc1t  = (u16*)(ws + 294912);
    u16*   fc2t  = (u16*)(ws + 589824);
    float* dwtf  = (float*)(ws + 884736);     // f32 [27][768] = 82,944 B
    u16*   r1    = (u16*)(ws + 1160192);      // xw / attnb / h2 (38,535,168 B)
    u16*   qkvb  = (u16*)(ws + 39695360LL);   // 115,605,504 B
    u16*   x2b   = (u16*)(ws + 39695360LL);   // bf16 residual (aliases dead qkvb)
    u16*   hid_c = (u16*)(ws + 78230528LL);   // per-batch [50176][768] bf16
    float* bmat  = (float*)(ws + 155300864LL);// [6][112][112] f32, dead before gelu
    u16*   gelu_c= (u16*)(ws + 155300864LL);  // per-batch [50176][768] bf16

    prep_weights<<<dim3(1809), dim3(256), 0, stream>>>(qkv_w, proj_w, fc1_w, fc2_w, dw_w,
                                                       qkvt, projt, fc1t, fc2t, dwtf);
    biasmat_kernel<<<dim3(294), dim3(256), 0, stream>>>(btab, bmat);
    ln_kernel<true, false><<<dim3(25088), dim3(256), 0, stream>>>(x, n1g, n1b, r1);
    gemm_bt<0><<<dim3(784, 9), dim3(256), 0, stream>>>(r1, qkvt, qkv_b, 192, 576,
                                                       qkvb, nullptr, nullptr, nullptr, 0);
    attn_mfma_kernel<<<dim3(1024, 6), dim3(64), 0, stream>>>(qkvb, bmat, r1);
    gemm_bt<1><<<dim3(784, 3), dim3(256), 0, stream>>>(r1, projt, proj_b, 192, 192,
                                                       nullptr, x, x2b, nullptr, 0);
    ln_kernel<false, true><<<dim3(25088), dim3(256), 0, stream>>>(x2b, n2g, n2b, r1);
    for (int b = 0; b < 2; b++) {
        const u16* h2c = r1 + (size_t)b * M_HALF * DIMC;
        gemm_bt<0><<<dim3(392, 12), dim3(256), 0, stream>>>(h2c, fc1t, fc1_b, 192, 768,
                                                            hid_c, nullptr, nullptr, nullptr, 0);
        dwconv_gelu_kernel<<<dim3(9408), dim3(256), 0, stream>>>(hid_c, dwtf, dw_b, gelu_c);
        gemm_bt<2><<<dim3(392, 3), dim3(256), 0, stream>>>(gelu_c, fc2t, fc2_b, 768, 192,
                                                           nullptr, nullptr, x2b, (float*)d_out,
                                                           b * M_HALF);
    }
}

// Round 8
// 728.865 us; speedup vs baseline: 1.6677x; 1.1494x over previous
//
#include <hip/hip_runtime.h>
#include <hip/hip_bf16.h>

typedef unsigned short u16;
typedef unsigned int   u32;
typedef __bf16 bf16x8 __attribute__((ext_vector_type(8)));
typedef float  f32x4  __attribute__((ext_vector_type(4)));
typedef float  f32x2  __attribute__((ext_vector_type(2)));

// Problem constants
#define M_TOK 100352      // B*N = 2*16*56*56 tokens
#define M_HALF 50176      // tokens per batch
#define DIMC  192
#define HIDC  768
#define SCALE_F 0.17677669529663688f

__device__ __forceinline__ float b2f(u16 u) {
    u32 x = ((u32)u) << 16; float f; __builtin_memcpy(&f, &x, 4); return f;
}
__device__ __forceinline__ u16 f2b(float f) {
    u32 x; __builtin_memcpy(&x, &f, 4);
    x = x + 0x7FFFu + ((x >> 16) & 1u);   // round-to-nearest-even
    return (u16)(x >> 16);
}
__device__ __forceinline__ float lo2f(u32 w) {  // low u16 -> f32
    u32 x = w << 16; float f; __builtin_memcpy(&f, &x, 4); return f;
}
__device__ __forceinline__ float hi2f(u32 w) {  // high u16 -> f32
    u32 x = w & 0xFFFF0000u; float f; __builtin_memcpy(&f, &x, 4); return f;
}
// async global->LDS, 16B per lane (dest must be linear in lane order)
__device__ __forceinline__ void g2l16(const u16* g, u16* l) {
    __builtin_amdgcn_global_load_lds(
        (const __attribute__((address_space(1))) u32*)g,
        (__attribute__((address_space(3))) u32*)l, 16, 0, 0);
}

// ---------------------------------------------------------------------------
// Weight prep: fp32 -> bf16 transposed [N][K] for GEMM B-operands;
// depthwise weights [768][27] -> f32 [27][768].
// ---------------------------------------------------------------------------
__global__ __launch_bounds__(256) void prep_weights(
    const float* __restrict__ qkv_w, const float* __restrict__ proj_w,
    const float* __restrict__ fc1_w, const float* __restrict__ fc2_w,
    const float* __restrict__ dw_w,
    u16* __restrict__ qkvt, u16* __restrict__ projt, u16* __restrict__ fc1t,
    u16* __restrict__ fc2t, float* __restrict__ dwtf)
{
    int id = blockIdx.x * 256 + threadIdx.x;
    if (id < 110592)      { int n = id / 192, k = id % 192;                 qkvt[id] = f2b(qkv_w[k * 576 + n]); }
    else if (id < 147456) { int e = id - 110592, n = e / 192, k = e % 192;  projt[e] = f2b(proj_w[k * 192 + n]); }
    else if (id < 294912) { int e = id - 147456, n = e / 192, k = e % 192;  fc1t[e]  = f2b(fc1_w[k * 768 + n]); }
    else if (id < 442368) { int e = id - 294912, n = e / 768, k = e % 768;  fc2t[e]  = f2b(fc2_w[k * 192 + n]); }
    else if (id < 463104) { int e = id - 442368, t = e / 768, c = e % 768;  dwtf[e]  = dw_w[c * 27 + t]; }
}

// ---------------------------------------------------------------------------
// Relative-position bias matrix, PADDED: bmat[head][112][112] f32.
// ---------------------------------------------------------------------------
__global__ __launch_bounds__(256) void biasmat_kernel(
    const float* __restrict__ btab, float* __restrict__ bmat)
{
    int id = blockIdx.x * 256 + threadIdx.x;
    if (id >= 6 * 112 * 112) return;
    int h = id / 12544, rem = id % 12544, i = rem / 112, j = rem % 112;
    float v;
    if (j >= 98)      v = -1e30f;
    else if (i >= 98) v = 0.0f;
    else {
        int di = i / 49, hi = (i / 7) % 7, wi = i % 7;
        int dj = j / 49, hj = (j / 7) % 7, wj = j % 7;
        int idx = (di - dj + 1) * 169 + (hi - hj + 6) * 13 + (wi - wj + 6);
        v = btab[idx * 6 + h];
    }
    bmat[id] = v;
}

// ---------------------------------------------------------------------------
// LayerNorm over 192; one wave per row. PERM=true writes window-major order.
// ---------------------------------------------------------------------------
template<bool PERM, bool BF_IN>
__global__ __launch_bounds__(256) void ln_kernel(
    const void* __restrict__ xin, const float* __restrict__ g,
    const float* __restrict__ bb, u16* __restrict__ out)
{
    int row  = blockIdx.x * 4 + (threadIdx.x >> 6);
    int lane = threadIdx.x & 63;
    float v0, v1, v2;
    if (BF_IN) {
        const u16* xr = (const u16*)xin + (size_t)row * DIMC;
        v0 = b2f(xr[lane]); v1 = b2f(xr[lane + 64]); v2 = b2f(xr[lane + 128]);
    } else {
        const float* xr = (const float*)xin + (size_t)row * DIMC;
        v0 = xr[lane]; v1 = xr[lane + 64]; v2 = xr[lane + 128];
    }
    float s  = v0 + v1 + v2;
    float s2 = v0 * v0 + v1 * v1 + v2 * v2;
    #pragma unroll
    for (int m = 1; m < 64; m <<= 1) { s += __shfl_xor(s, m); s2 += __shfl_xor(s2, m); }
    float mu = s * (1.0f / 192.0f);
    float rs = rsqrtf(s2 * (1.0f / 192.0f) - mu * mu + 1e-5f);
    size_t ob;
    if (PERM) {
        int b = row / 50176, r = row % 50176;
        int d = r / 3136, r2 = r % 3136, h = r2 / 56, w = r2 % 56;
        int widx = ((b * 8 + (d >> 1)) * 8 + h / 7) * 8 + w / 7;
        int tok  = (d & 1) * 49 + (h % 7) * 7 + (w % 7);
        ob = ((size_t)widx * 98 + tok) * DIMC;
    } else {
        ob = (size_t)row * DIMC;
    }
    out[ob + lane]       = f2b((v0 - mu) * rs * g[lane]       + bb[lane]);
    out[ob + lane + 64]  = f2b((v1 - mu) * rs * g[lane + 64]  + bb[lane + 64]);
    out[ob + lane + 128] = f2b((v2 - mu) * rs * g[lane + 128] + bb[lane + 128]);
}

// ---------------------------------------------------------------------------
// bf16 MFMA GEMM: C[M,N] = A[M,K] * Bt[N,K]^T + bias
// BM=128, BN=64, BK=32, 256 threads. global_load_lds width-16 staging
// (LDS dest linear in thread order = wave-uniform base + lane*16).
// 1D grid, n-fastest tile order (A-tile reuse in L2) + XCD chunk swizzle.
// ---------------------------------------------------------------------------
template<int EPI>
__global__ __launch_bounds__(256) void gemm_bt(
    const u16* __restrict__ A, const u16* __restrict__ Bt,
    const float* __restrict__ bias, int K, int N, int NBN,
    u16* __restrict__ outb, const float* __restrict__ xres,
    u16* __restrict__ x2b, float* __restrict__ outf, int mofs)
{
    __shared__ __align__(16) u16 Alds[128 * 32];
    __shared__ __align__(16) u16 Blds[64 * 32];
    int bid = blockIdx.x;
    int cpx = gridDim.x >> 3;                 // grids are multiples of 8
    int swz = (bid & 7) * cpx + (bid >> 3);   // XCD-contiguous chunks
    int m0 = (swz / NBN) * 128;
    int n0 = (swz % NBN) * 64;
    int t  = threadIdx.x;
    int ar = t >> 2, ac = (t & 3) * 8;
    int lane = t & 63, wid = t >> 6;
    int wm = wid >> 1, wn = wid & 1;
    int lrow = lane & 15, lko = (lane >> 4) * 8;
    const u16* Ag  = A  + (size_t)(m0 + ar) * K + ac;
    const u16* Ag2 = Ag + (size_t)64 * K;
    const u16* Bg  = Bt + (size_t)(n0 + ar) * K + ac;
    u16* lA  = Alds + t * 8;
    u16* lA2 = Alds + 2048 + t * 8;
    u16* lB  = Blds + t * 8;
    f32x4 acc[4][2] = {};
    for (int kt = 0; kt < K; kt += 32) {
        __syncthreads();
        g2l16(Ag  + kt, lA);
        g2l16(Ag2 + kt, lA2);
        g2l16(Bg  + kt, lB);
        __syncthreads();                      // barrier drains vmcnt -> LDS valid
        bf16x8 af[4], bfr[2];
        #pragma unroll
        for (int mi = 0; mi < 4; mi++)
            af[mi] = *(const bf16x8*)&Alds[(wm * 64 + mi * 16 + lrow) * 32 + lko];
        #pragma unroll
        for (int ni = 0; ni < 2; ni++)
            bfr[ni] = *(const bf16x8*)&Blds[(wn * 32 + ni * 16 + lrow) * 32 + lko];
        #pragma unroll
        for (int mi = 0; mi < 4; mi++)
            #pragma unroll
            for (int ni = 0; ni < 2; ni++)
                acc[mi][ni] = __builtin_amdgcn_mfma_f32_16x16x32_bf16(af[mi], bfr[ni], acc[mi][ni], 0, 0, 0);
    }
    int r0 = (lane >> 4) * 4, cl = lane & 15;
    #pragma unroll
    for (int ni = 0; ni < 2; ni++) {
        int col = n0 + wn * 32 + ni * 16 + cl;
        float bv = bias[col];
        #pragma unroll
        for (int mi = 0; mi < 4; mi++) {
            #pragma unroll
            for (int r = 0; r < 4; r++) {
                int row = m0 + wm * 64 + mi * 16 + r0 + r;
                float v = acc[mi][ni][r] + bv;
                if (EPI == 0) {
                    outb[(size_t)row * N + col] = f2b(v);
                } else if (EPI == 1) {
                    int widx = row / 98, tok = row % 98;
                    int b = widx >> 9, rem = widx & 511;
                    int bd = rem >> 6, bh = (rem >> 3) & 7, bw = rem & 7;
                    int td = tok / 49, rr = tok % 49, th = rr / 7, tw = rr % 7;
                    int d = bd * 2 + td, h = bh * 7 + th, w = bw * 7 + tw;
                    size_t gg = ((size_t)b * 50176 + (d * 56 + h) * 56 + w) * (size_t)N + col;
                    x2b[gg] = f2b(xres[gg] + 0.5f * v);
                } else {
                    size_t gg = (size_t)(row + mofs) * N + col;
                    outf[gg] = b2f(x2b[gg]) + 0.5f * v;
                }
            }
        }
    }
}

// ---------------------------------------------------------------------------
// MFMA window attention: 1 wave per (window, head). 98 tokens padded to 112.
// ---------------------------------------------------------------------------
__global__ __launch_bounds__(64) void attn_mfma_kernel(
    const u16* __restrict__ qkv, const float* __restrict__ bmat,
    u16* __restrict__ outb)
{
    __shared__ __align__(16) u16 Klds[112 * 40];
    __shared__ __align__(16) u16 Vt[32 * 136];
    __shared__ __align__(16) u16 Plds[16 * 136];
    int widx = blockIdx.x, head = blockIdx.y;
    int l = threadIdx.x;
    int c = l & 15, g = l >> 4;
    size_t wbase = (size_t)widx * (98 * 576) + head * 32;

    for (int e = l; e < 448; e += 64) {
        int rr = e >> 2, seg = (e & 3) * 8;
        uint4 kr = {0, 0, 0, 0}, vr = {0, 0, 0, 0};
        if (rr < 98) {
            kr = *(const uint4*)(qkv + wbase + (size_t)rr * 576 + 192 + seg);
            vr = *(const uint4*)(qkv + wbase + (size_t)rr * 576 + 384 + seg);
        }
        *(uint4*)&Klds[rr * 40 + seg] = kr;
        int sw = ((seg >> 3) & 3) << 4;
        int pc = rr ^ sw;
        const u16* vp = (const u16*)&vr;
        #pragma unroll
        for (int u = 0; u < 8; u++)
            Vt[(seg + u) * 136 + pc] = vp[u];
    }
    {
        int d = l >> 1, half = l & 1;
        int sw = ((d >> 3) & 3) << 4;
        uint4 z = {0, 0, 0, 0};
        *(uint4*)&Vt[d * 136 + ((112 + 8 * half) ^ sw)] = z;
        if (l < 32) {
            int i = l >> 1; half = l & 1;
            int swp = ((i >> 2) & 3) << 4;
            *(uint4*)&Plds[i * 136 + ((112 + 8 * half) ^ swp)] = z;
        }
    }

    for (int it = 0; it < 7; ++it) {
        int qtok = 16 * it + c; if (qtok > 97) qtok = 97;
        bf16x8 qf = *(const bf16x8*)(qkv + wbase + (size_t)qtok * 576 + g * 8);
        f32x4 s[7];
        f32x4 z = {};
        #pragma unroll
        for (int jt = 0; jt < 7; ++jt) {
            bf16x8 kf = *(const bf16x8*)&Klds[(16 * jt + c) * 40 + g * 8];
            s[jt] = __builtin_amdgcn_mfma_f32_16x16x32_bf16(qf, kf, z, 0, 0, 0);
        }
        const float* bb = bmat + ((size_t)head * 112 + 16 * it + 4 * g) * 112 + c;
        float sm[4];
        #pragma unroll
        for (int r = 0; r < 4; ++r) {
            float m = -1e30f;
            #pragma unroll
            for (int jt = 0; jt < 7; ++jt) {
                float v = s[jt][r] * SCALE_F + bb[r * 112 + 16 * jt];
                s[jt][r] = v;
                m = fmaxf(m, v);
            }
            m = fmaxf(m, __shfl_xor(m, 1)); m = fmaxf(m, __shfl_xor(m, 2));
            m = fmaxf(m, __shfl_xor(m, 4)); m = fmaxf(m, __shfl_xor(m, 8));
            float su = 0.f;
            #pragma unroll
            for (int jt = 0; jt < 7; ++jt) {
                float p = __expf(s[jt][r] - m);
                s[jt][r] = p;
                su += p;
            }
            su += __shfl_xor(su, 1); su += __shfl_xor(su, 2);
            su += __shfl_xor(su, 4); su += __shfl_xor(su, 8);
            sm[r] = su;
        }
        #pragma unroll
        for (int r = 0; r < 4; ++r) {
            int prow = 4 * g + r;
            int swp = ((prow >> 2) & 3) << 4;
            #pragma unroll
            for (int jt = 0; jt < 7; ++jt)
                Plds[prow * 136 + ((16 * jt + c) ^ swp)] = f2b(s[jt][r]);
        }
        bf16x8 pa[4];
        int swr = ((c >> 2) & 3) << 4;
        #pragma unroll
        for (int ks = 0; ks < 4; ++ks)
            pa[ks] = *(const bf16x8*)&Plds[c * 136 + ((32 * ks + 8 * g) ^ swr)];
        #pragma unroll
        for (int dt = 0; dt < 2; ++dt) {
            f32x4 o = {};
            int vrow = 16 * dt + c;
            int swv = ((vrow >> 3) & 3) << 4;
            #pragma unroll
            for (int ks = 0; ks < 4; ++ks) {
                bf16x8 vb = *(const bf16x8*)&Vt[vrow * 136 + ((32 * ks + 8 * g) ^ swv)];
                o = __builtin_amdgcn_mfma_f32_16x16x32_bf16(pa[ks], vb, o, 0, 0, 0);
            }
            #pragma unroll
            for (int r = 0; r < 4; ++r) {
                int row = 16 * it + 4 * g + r;
                if (row < 98)
                    outb[((size_t)widx * 98 + row) * DIMC + head * 32 + 16 * dt + c]
                        = f2b(o[r] / sm[r]);
            }
        }
    }
}

// ---------------------------------------------------------------------------
// Depthwise 3x3x3 conv + sigmoid-form GELU.
// Thread = 4 outputs along w x 4 channels (w over-read 1.5x, cvt once per
// position, reused across taps). d-fastest mapping + XCD chunk swizzle.
// Live regs ~55 < 64-VGPR cliff.
// ---------------------------------------------------------------------------
__global__ __launch_bounds__(256, 8) void dwconv_gelu_kernel(
    const u16* __restrict__ hid, const float* __restrict__ dwtf,
    const float* __restrict__ dwb, u16* __restrict__ outb)
{
    int bid = blockIdx.x;
    int swz = (bid & 7) * 1176 + (bid >> 3);   // 9408 blocks / 8 XCDs
    int gid = swz * 256 + threadIdx.x;
    int cg = gid % 192;
    int t  = gid / 192;
    int d  = t & 15;
    t >>= 4;
    int wg = t % 14;
    int h  = t / 14;                  // 0..55
    int w0 = wg * 4;
    int c0 = cg * 4;

    f32x2 acc[4][2];
    {
        float4 bv = *(const float4*)(dwb + c0);
        #pragma unroll
        for (int wi = 0; wi < 4; ++wi) {
            acc[wi][0] = f32x2{bv.x, bv.y};
            acc[wi][1] = f32x2{bv.z, bv.w};
        }
    }

    #pragma unroll
    for (int iz = 0; iz < 3; ++iz) {
        int zz = d - 1 + iz;
        if ((unsigned)zz >= 16u) continue;
        #pragma unroll
        for (int iy = 0; iy < 3; ++iy) {
            int yy = h - 1 + iy;
            if ((unsigned)yy >= 56u) continue;
            uint2 raw[6];
            const u16* rp = hid + ((size_t)(zz * 56 + yy) * 56 + w0 - 1) * HIDC + c0;
            #pragma unroll
            for (int ix = 0; ix < 6; ++ix) {
                uint2 iv = {0, 0};
                if ((unsigned)(w0 - 1 + ix) < 56u)
                    iv = *(const uint2*)(rp + (size_t)ix * HIDC);
                raw[ix] = iv;
            }
            const float* wrow = dwtf + (size_t)(iz * 9 + iy * 3) * HIDC + c0;
            float4 wv0 = *(const float4*)(wrow);
            float4 wv1 = *(const float4*)(wrow + HIDC);
            float4 wv2 = *(const float4*)(wrow + 2 * HIDC);
            f32x2 wp[3][2] = {
                { f32x2{wv0.x, wv0.y}, f32x2{wv0.z, wv0.w} },
                { f32x2{wv1.x, wv1.y}, f32x2{wv1.z, wv1.w} },
                { f32x2{wv2.x, wv2.y}, f32x2{wv2.z, wv2.w} } };
            #pragma unroll
            for (int p = 0; p < 6; ++p) {
                f32x2 i0 = f32x2{lo2f(raw[p].x), hi2f(raw[p].x)};
                f32x2 i1 = f32x2{lo2f(raw[p].y), hi2f(raw[p].y)};
                #pragma unroll
                for (int dx = 0; dx < 3; ++dx) {
                    if (dx > p || dx < p - 3) continue;   // compile-time pruned
                    acc[p - dx][0] += i0 * wp[dx][0];
                    acc[p - dx][1] += i1 * wp[dx][1];
                }
            }
        }
    }

    size_t tok0 = (size_t)(d * 56 + h) * 56 + w0;
    #pragma unroll
    for (int wi = 0; wi < 4; ++wi) {
        u16 res[4];
        #pragma unroll
        for (int pr = 0; pr < 2; ++pr) {
            #pragma unroll
            for (int u = 0; u < 2; ++u) {
                float a = acc[wi][pr][u];
                float tt = a * (1.5957691216f + 0.0713548162f * a * a);
                res[pr * 2 + u] = f2b(a / (1.0f + __expf(-tt)));
            }
        }
        uint2 ov;
        ov.x = (u32)res[0] | ((u32)res[1] << 16);
        ov.y = (u32)res[2] | ((u32)res[3] << 16);
        *(uint2*)(outb + (tok0 + wi) * HIDC + c0) = ov;
    }
}

// ---------------------------------------------------------------------------
// Orchestration (workspace layout unchanged).
// ---------------------------------------------------------------------------
extern "C" void kernel_launch(void* const* d_in, const int* in_sizes, int n_in,
                              void* d_out, int out_size, void* d_ws, size_t ws_size,
                              hipStream_t stream)
{
    const float* x      = (const float*)d_in[0];
    const float* n1g    = (const float*)d_in[1];
    const float* n1b    = (const float*)d_in[2];
    const float* qkv_w  = (const float*)d_in[3];
    const float* qkv_b  = (const float*)d_in[4];
    const float* btab   = (const float*)d_in[5];
    const float* proj_w = (const float*)d_in[6];
    const float* proj_b = (const float*)d_in[7];
    const float* n2g    = (const float*)d_in[8];
    const float* n2b    = (const float*)d_in[9];
    const float* fc1_w  = (const float*)d_in[10];
    const float* fc1_b  = (const float*)d_in[11];
    const float* dw_w   = (const float*)d_in[12];
    const float* dw_b   = (const float*)d_in[13];
    const float* fc2_w  = (const float*)d_in[14];
    const float* fc2_b  = (const float*)d_in[15];

    char* ws = (char*)d_ws;
    u16*   qkvt  = (u16*)(ws);
    u16*   projt = (u16*)(ws + 221184);
    u16*   fc1t  = (u16*)(ws + 294912);
    u16*   fc2t  = (u16*)(ws + 589824);
    float* dwtf  = (float*)(ws + 884736);     // f32 [27][768] = 82,944 B
    u16*   r1    = (u16*)(ws + 1160192);      // xw / attnb / h2 (38,535,168 B)
    u16*   qkvb  = (u16*)(ws + 39695360LL);   // 115,605,504 B
    u16*   x2b   = (u16*)(ws + 39695360LL);   // bf16 residual (aliases dead qkvb)
    u16*   hid_c = (u16*)(ws + 78230528LL);   // per-batch [50176][768] bf16
    float* bmat  = (float*)(ws + 155300864LL);// [6][112][112] f32, dead before gelu
    u16*   gelu_c= (u16*)(ws + 155300864LL);  // per-batch [50176][768] bf16

    prep_weights<<<dim3(1809), dim3(256), 0, stream>>>(qkv_w, proj_w, fc1_w, fc2_w, dw_w,
                                                       qkvt, projt, fc1t, fc2t, dwtf);
    biasmat_kernel<<<dim3(294), dim3(256), 0, stream>>>(btab, bmat);
    ln_kernel<true, false><<<dim3(25088), dim3(256), 0, stream>>>(x, n1g, n1b, r1);
    // QKV: 784 m-blocks x 9 n-blocks, n fastest
    gemm_bt<0><<<dim3(7056), dim3(256), 0, stream>>>(r1, qkvt, qkv_b, 192, 576, 9,
                                                     qkvb, nullptr, nullptr, nullptr, 0);
    attn_mfma_kernel<<<dim3(1024, 6), dim3(64), 0, stream>>>(qkvb, bmat, r1);
    // proj: 784 x 3
    gemm_bt<1><<<dim3(2352), dim3(256), 0, stream>>>(r1, projt, proj_b, 192, 192, 3,
                                                     nullptr, x, x2b, nullptr, 0);
    ln_kernel<false, true><<<dim3(25088), dim3(256), 0, stream>>>(x2b, n2g, n2b, r1);
    for (int b = 0; b < 2; b++) {
        const u16* h2c = r1 + (size_t)b * M_HALF * DIMC;
        // FC1: 392 x 12
        gemm_bt<0><<<dim3(4704), dim3(256), 0, stream>>>(h2c, fc1t, fc1_b, 192, 768, 12,
                                                         hid_c, nullptr, nullptr, nullptr, 0);
        dwconv_gelu_kernel<<<dim3(9408), dim3(256), 0, stream>>>(hid_c, dwtf, dw_b, gelu_c);
        // FC2: 392 x 3
        gemm_bt<2><<<dim3(1176), dim3(256), 0, stream>>>(gelu_c, fc2t, fc2_b, 768, 192, 3,
                                                         nullptr, nullptr, x2b, (float*)d_out,
                                                         b * M_HALF);
    }
}